// Round 2
// baseline (544.846 us; speedup 1.0000x reference)
//
#include <hip/hip_runtime.h>

typedef unsigned short u16;
typedef __attribute__((ext_vector_type(8))) short short8;
typedef __attribute__((ext_vector_type(4))) float f32x4;
typedef __attribute__((ext_vector_type(4))) int int4v;

constexpr int Bsz = 2, Ssz = 4096, Hn = 16, Dh = 128, HID = 2048;
constexpr int Cch = 128, NCh = 32;
constexpr float EPSf = 1e-6f;

__device__ __forceinline__ float b2f(u16 u) {
  unsigned int i = ((unsigned int)u) << 16;
  return __builtin_bit_cast(float, i);
}
__device__ __forceinline__ u16 f2b(float f) {
  unsigned int i = __builtin_bit_cast(unsigned int, f);
  i += 0x7fffu + ((i >> 16) & 1u);   // round-to-nearest-even
  return (u16)(i >> 16);
}

// ---------------------------------------------------------------------------
// Weight transpose+convert: W f32 [K][N] -> WT bf16 [N][K], 64x64 tiles.
// ---------------------------------------------------------------------------
__global__ __launch_bounds__(256) void transpose4(
    const float* __restrict__ A0, const float* __restrict__ A1,
    const float* __restrict__ A2, const float* __restrict__ A3,
    u16* __restrict__ T0, u16* __restrict__ T1,
    u16* __restrict__ T2, u16* __restrict__ T3)
{
  constexpr int N = HID, LDT = 72;
  const int z = blockIdx.z;
  const float* __restrict__ A = (z == 0) ? A0 : (z == 1) ? A1 : (z == 2) ? A2 : A3;
  u16* __restrict__ T = (z == 0) ? T0 : (z == 1) ? T1 : (z == 2) ? T2 : T3;
  __shared__ u16 lds[64 * LDT];
  const int t = threadIdx.x;
  const int i = t >> 3, j = (t & 7) * 8;
  const int r0 = blockIdx.y * 64, c0 = blockIdx.x * 64;
#pragma unroll
  for (int half = 0; half < 2; ++half) {
    const int r = i + half * 32;
    const f32x4 a = *(const f32x4*)&A[(size_t)(r0 + r) * N + c0 + j];
    const f32x4 b = *(const f32x4*)&A[(size_t)(r0 + r) * N + c0 + j + 4];
    u16 tmp[8];
#pragma unroll
    for (int u = 0; u < 4; ++u) { tmp[u] = f2b(a[u]); tmp[u + 4] = f2b(b[u]); }
    *(int4v*)&lds[r * LDT + j] = *(const int4v*)tmp;
  }
  __syncthreads();
#pragma unroll
  for (int half = 0; half < 2; ++half) {
    const int c = i + half * 32;
    u16 tmp[8];
#pragma unroll
    for (int u = 0; u < 8; ++u) tmp[u] = lds[(j + u) * LDT + c];
    *(int4v*)&T[(size_t)(c0 + c) * N + r0 + j] = *(const int4v*)tmp;
  }
}

// ---------------------------------------------------------------------------
// GEMM: out[m][n] = A[m][:] . WT[n][:] + bias[n], optional elu(x)+1 epilogue.
// 128x128 tile, BK=64, 4 waves (2x2), mfma_f32_16x16x32_bf16, f32 accum.
// AF32: A operand is f32 (converted to bf16 during LDS staging).
// OUTF32: output written as f32, else bf16.
// grid.z selects one of up to 3 weight/bias/out sets (QKV fused launch).
// ---------------------------------------------------------------------------
template <int AF32, int OUTF32>
__global__ __launch_bounds__(256) void gemm_bias(
    const void* __restrict__ Ap,
    const u16* __restrict__ W0T, const u16* __restrict__ W1T, const u16* __restrict__ W2T,
    const float* __restrict__ bb0, const float* __restrict__ bb1, const float* __restrict__ bb2,
    void* __restrict__ o0, void* __restrict__ o1, void* __restrict__ o2,
    int elu_mask)
{
  constexpr int K = HID, N = HID, BK = 64, LDK = BK + 8;   // stride 72 elems = 9 x 16B (odd) -> conflict-free
  const int z = blockIdx.z;
  const u16* __restrict__ WT   = (z == 0) ? W0T : (z == 1) ? W1T : W2T;
  const float* __restrict__ bias = (z == 0) ? bb0 : (z == 1) ? bb1 : bb2;
  void* __restrict__ outv = (z == 0) ? o0 : (z == 1) ? o1 : o2;
  const bool elu = (elu_mask >> z) & 1;

  __shared__ u16 lA[128 * LDK];
  __shared__ u16 lB[128 * LDK];

  const int t = threadIdx.x;
  const int lane = t & 63, w = t >> 6;
  const int wr = (w >> 1) * 64, wc = (w & 1) * 64;
  const int m0 = blockIdx.y * 128, n0 = blockIdx.x * 128;
  const int l15 = lane & 15, lg = lane >> 4;
  const int sr = t >> 3, sc = (t & 7) * 8;

  f32x4 acc[4][4] = {};

  for (int kt = 0; kt < K / BK; ++kt) {
    const int k0 = kt * BK;
#pragma unroll
    for (int rep = 0; rep < 4; ++rep) {
      const int r = rep * 32 + sr;
      if (AF32) {
        const float* Af = (const float*)Ap;
        const f32x4 a = *(const f32x4*)&Af[(size_t)(m0 + r) * K + k0 + sc];
        const f32x4 b = *(const f32x4*)&Af[(size_t)(m0 + r) * K + k0 + sc + 4];
        u16 tmp[8];
#pragma unroll
        for (int u = 0; u < 4; ++u) { tmp[u] = f2b(a[u]); tmp[u + 4] = f2b(b[u]); }
        *(int4v*)&lA[r * LDK + sc] = *(const int4v*)tmp;
      } else {
        const u16* Ab = (const u16*)Ap;
        *(int4v*)&lA[r * LDK + sc] = *(const int4v*)&Ab[(size_t)(m0 + r) * K + k0 + sc];
      }
      *(int4v*)&lB[r * LDK + sc] = *(const int4v*)&WT[(size_t)(n0 + r) * K + k0 + sc];
    }
    __syncthreads();
#pragma unroll
    for (int kk = 0; kk < 2; ++kk) {
      const int krd = kk * 32 + lg * 8;
      short8 aF[4], bF[4];
#pragma unroll
      for (int i = 0; i < 4; ++i)
        aF[i] = *(const short8*)&lA[(wr + i * 16 + l15) * LDK + krd];
#pragma unroll
      for (int j = 0; j < 4; ++j)
        bF[j] = *(const short8*)&lB[(wc + j * 16 + l15) * LDK + krd];
#pragma unroll
      for (int i = 0; i < 4; ++i)
#pragma unroll
        for (int j = 0; j < 4; ++j)
          acc[i][j] = __builtin_amdgcn_mfma_f32_16x16x32_bf16(aF[i], bF[j], acc[i][j], 0, 0, 0);
    }
    __syncthreads();
  }

#pragma unroll
  for (int j = 0; j < 4; ++j) {
    const int col = n0 + wc + j * 16 + l15;
    const float bv = bias[col];
#pragma unroll
    for (int i = 0; i < 4; ++i) {
      const int row0 = m0 + wr + i * 16 + lg * 4;
#pragma unroll
      for (int r = 0; r < 4; ++r) {
        float v = acc[i][j][r] + bv;
        if (elu) v = (v > 0.0f) ? (v + 1.0f) : __expf(v);   // elu(x)+1
        if (OUTF32) ((float*)outv)[(size_t)(row0 + r) * N + col] = v;
        else        ((u16*)outv)[(size_t)(row0 + r) * N + col] = f2b(v);
      }
    }
  }
}

// ---------------------------------------------------------------------------
// Pass 1, per (b,n,h): kvT[e][d] = sum_c v[c,e]*kf[c,d];  ksum[d] = sum_c kf[c,d]
// ---------------------------------------------------------------------------
__global__ __launch_bounds__(256) void pass1_kv(
    const u16* __restrict__ KF, const u16* __restrict__ V,
    u16* __restrict__ KVT, float* __restrict__ KSUM)
{
  constexpr int LD = 136;
  __shared__ u16 lk[128 * LD];
  __shared__ u16 lv[128 * LD];
  const int bnh = blockIdx.x;
  const int h = bnh % Hn, n = (bnh / Hn) % NCh, b = bnh / (Hn * NCh);
  const size_t rowbase = (size_t)(b * Ssz + n * Cch) * HID + h * Dh;
  const int t = threadIdx.x, lane = t & 63, w = t >> 6;
  const int wr = (w >> 1) * 64, wc = (w & 1) * 64;
  const int l15 = lane & 15, lg = lane >> 4;
  const int sr = t >> 4, sc = (t & 15) * 8;

#pragma unroll
  for (int rep = 0; rep < 8; ++rep) {
    const int r = rep * 16 + sr;
    *(int4v*)&lk[r * LD + sc] = *(const int4v*)&KF[rowbase + (size_t)r * HID + sc];
    *(int4v*)&lv[r * LD + sc] = *(const int4v*)&V[rowbase + (size_t)r * HID + sc];
  }
  __syncthreads();

  if (t < 128) {
    float s = 0.0f;
    for (int c = 0; c < 128; ++c) s += b2f(lk[c * LD + t]);
    KSUM[(size_t)bnh * Dh + t] = s;
  }

  f32x4 acc[4][4] = {};
#pragma unroll
  for (int kk = 0; kk < 4; ++kk) {
    const int cb = kk * 32 + lg * 8;
    short8 aF[4], bF[4];
#pragma unroll
    for (int i = 0; i < 4; ++i) {           // A[e][c] = v[c][e]  (transposed read)
      const int e = wr + i * 16 + l15;
      short8 a;
#pragma unroll
      for (int u = 0; u < 8; ++u) a[u] = (short)lv[(cb + u) * LD + e];
      aF[i] = a;
    }
#pragma unroll
    for (int j = 0; j < 4; ++j) {           // B[c][d] = kf[c][d]  (transposed read)
      const int d = wc + j * 16 + l15;
      short8 bb;
#pragma unroll
      for (int u = 0; u < 8; ++u) bb[u] = (short)lk[(cb + u) * LD + d];
      bF[j] = bb;
    }
#pragma unroll
    for (int i = 0; i < 4; ++i)
#pragma unroll
      for (int j = 0; j < 4; ++j)
        acc[i][j] = __builtin_amdgcn_mfma_f32_16x16x32_bf16(aF[i], bF[j], acc[i][j], 0, 0, 0);
  }

  u16* __restrict__ outp = KVT + (size_t)bnh * (Dh * Dh);
#pragma unroll
  for (int i = 0; i < 4; ++i) {
    const int e0 = wr + i * 16 + lg * 4;
#pragma unroll
    for (int j = 0; j < 4; ++j) {
      const int d = wc + j * 16 + l15;
#pragma unroll
      for (int r = 0; r < 4; ++r)
        outp[(size_t)(e0 + r) * Dh + d] = f2b(acc[i][j][r]);
    }
  }
}

// ---------------------------------------------------------------------------
// Exclusive cumsum over chunks, in place (f32 running sum).
// ---------------------------------------------------------------------------
__global__ __launch_bounds__(256) void cumsum_kv(u16* __restrict__ KVT) {
  const int tid = blockIdx.x * 256 + threadIdx.x;        // B*H*D*D threads
  const int ed = tid & (Dh * Dh - 1);
  const int bh = tid >> 14;
  const int h = bh % Hn, b = bh / Hn;
  const size_t base = ((size_t)(b * NCh * Hn) + h) * (Dh * Dh) + ed;
  const size_t stride = (size_t)Hn * Dh * Dh;
  float s = 0.0f;
  for (int n = 0; n < NCh; ++n) {
    const size_t idx = base + (size_t)n * stride;
    const float v = b2f(KVT[idx]);
    KVT[idx] = f2b(s);
    s += v;
  }
}

__global__ __launch_bounds__(256) void cumsum_ks(float* __restrict__ KS) {
  const int tid = blockIdx.x * 256 + threadIdx.x;        // B*H*D threads
  const int d = tid & (Dh - 1);
  const int bh = tid >> 7;
  const int h = bh % Hn, b = bh / Hn;
  const size_t base = ((size_t)(b * NCh * Hn) + h) * Dh + d;
  const size_t stride = (size_t)Hn * Dh;
  float s = 0.0f;
  for (int n = 0; n < NCh; ++n) {
    const size_t idx = base + (size_t)n * stride;
    const float v = KS[idx];
    KS[idx] = s;
    s += v;
  }
}

// ---------------------------------------------------------------------------
// Pass 2, per (b,n,h): A = tril(qf.kf^T); y = (A.v + qf.kv_ex) / (z_intra+z_inter+eps)
// Y may alias QF (each block reads its QF rows into LDS before writing Y).
// ---------------------------------------------------------------------------
__global__ __launch_bounds__(256) void pass2_attn(
    const u16* __restrict__ QF, const u16* __restrict__ KF, const u16* __restrict__ V,
    const u16* __restrict__ KVT, const float* __restrict__ KSE,
    u16* __restrict__ Y)
{
  constexpr int LD = 136;
  __shared__ u16 smem[4 * 128 * LD];
  __shared__ float zbuf[128];
  u16* sQ  = smem;
  u16* sK  = smem + 128 * LD;      // kf, later reused for v
  u16* sA  = smem + 2 * 128 * LD;
  u16* sKV = smem + 3 * 128 * LD;

  const int bnh = blockIdx.x;
  const int h = bnh % Hn, n = (bnh / Hn) % NCh, b = bnh / (Hn * NCh);
  const size_t rowbase = (size_t)(b * Ssz + n * Cch) * HID + h * Dh;
  const int t = threadIdx.x, lane = t & 63, w = t >> 6;
  const int wr = (w >> 1) * 64, wc = (w & 1) * 64;
  const int l15 = lane & 15, lg = lane >> 4;
  const int sr = t >> 4, sc = (t & 15) * 8;

  const u16* __restrict__ kvsrc = KVT + (size_t)bnh * (Dh * Dh);
#pragma unroll
  for (int rep = 0; rep < 8; ++rep) {
    const int r = rep * 16 + sr;
    *(int4v*)&sQ[r * LD + sc]  = *(const int4v*)&QF[rowbase + (size_t)r * HID + sc];
    *(int4v*)&sK[r * LD + sc]  = *(const int4v*)&KF[rowbase + (size_t)r * HID + sc];
    *(int4v*)&sKV[r * LD + sc] = *(const int4v*)&kvsrc[r * Dh + sc];
  }
  __syncthreads();

  // --- QK^T (contraction over d; both operands natural K-contig reads) ---
  f32x4 acc[4][4] = {};
#pragma unroll
  for (int kk = 0; kk < 4; ++kk) {
    const int krd = kk * 32 + lg * 8;
    short8 aF[4], bF[4];
#pragma unroll
    for (int i = 0; i < 4; ++i)
      aF[i] = *(const short8*)&sQ[(wr + i * 16 + l15) * LD + krd];
#pragma unroll
    for (int j = 0; j < 4; ++j)
      bF[j] = *(const short8*)&sK[(wc + j * 16 + l15) * LD + krd];
#pragma unroll
    for (int i = 0; i < 4; ++i)
#pragma unroll
      for (int j = 0; j < 4; ++j)
        acc[i][j] = __builtin_amdgcn_mfma_f32_16x16x32_bf16(aF[i], bF[j], acc[i][j], 0, 0, 0);
  }
  // causal mask + write A to LDS (bf16)
#pragma unroll
  for (int i = 0; i < 4; ++i) {
    const int c0 = wr + i * 16 + lg * 4;
#pragma unroll
    for (int j = 0; j < 4; ++j) {
      const int ck = wc + j * 16 + l15;
#pragma unroll
      for (int r = 0; r < 4; ++r) {
        const int c = c0 + r;
        sA[c * LD + ck] = f2b((ck <= c) ? acc[i][j][r] : 0.0f);
      }
    }
  }
  __syncthreads();

  // --- z per row (threads 0..127) + stage V over kf (all threads) ---
  if (t < 128) {
    const float* kse = KSE + (size_t)bnh * Dh;
    float zz = EPSf;
    for (int d2 = 0; d2 < 128; ++d2) zz += b2f(sQ[t * LD + d2]) * kse[d2];
    for (int ck = 0; ck < 128; ++ck) zz += b2f(sA[t * LD + ck]);
    zbuf[t] = zz;
  }
#pragma unroll
  for (int rep = 0; rep < 8; ++rep) {
    const int r = rep * 16 + sr;
    *(int4v*)&sK[r * LD + sc] = *(const int4v*)&V[rowbase + (size_t)r * HID + sc];
  }
  __syncthreads();

  // --- intra: o += A . v   (B operand transposed read) ---
  f32x4 o[4][4] = {};
#pragma unroll
  for (int kk = 0; kk < 4; ++kk) {
    const int krd = kk * 32 + lg * 8;
    short8 aF[4], bF[4];
#pragma unroll
    for (int i = 0; i < 4; ++i)
      aF[i] = *(const short8*)&sA[(wr + i * 16 + l15) * LD + krd];
#pragma unroll
    for (int j = 0; j < 4; ++j) {
      const int e = wc + j * 16 + l15;
      short8 bb;
#pragma unroll
      for (int u = 0; u < 8; ++u) bb[u] = (short)sK[(krd + u) * LD + e];
      bF[j] = bb;
    }
#pragma unroll
    for (int i = 0; i < 4; ++i)
#pragma unroll
      for (int j = 0; j < 4; ++j)
        o[i][j] = __builtin_amdgcn_mfma_f32_16x16x32_bf16(aF[i], bF[j], o[i][j], 0, 0, 0);
  }
  // --- inter: o += qf . kv_ex  (kvT stored [e][d] -> natural reads) ---
#pragma unroll
  for (int kk = 0; kk < 4; ++kk) {
    const int krd = kk * 32 + lg * 8;
    short8 aF[4], bF[4];
#pragma unroll
    for (int i = 0; i < 4; ++i)
      aF[i] = *(const short8*)&sQ[(wr + i * 16 + l15) * LD + krd];
#pragma unroll
    for (int j = 0; j < 4; ++j)
      bF[j] = *(const short8*)&sKV[(wc + j * 16 + l15) * LD + krd];
#pragma unroll
    for (int i = 0; i < 4; ++i)
#pragma unroll
      for (int j = 0; j < 4; ++j)
        o[i][j] = __builtin_amdgcn_mfma_f32_16x16x32_bf16(aF[i], bF[j], o[i][j], 0, 0, 0);
  }

  // --- normalize + store y ---
#pragma unroll
  for (int i = 0; i < 4; ++i) {
    const int c0 = wr + i * 16 + lg * 4;
#pragma unroll
    for (int j = 0; j < 4; ++j) {
      const int e = wc + j * 16 + l15;
#pragma unroll
      for (int r = 0; r < 4; ++r) {
        const int c = c0 + r;
        Y[rowbase + (size_t)c * HID + e] = f2b(o[i][j][r] / zbuf[c]);
      }
    }
  }
}

// ---------------------------------------------------------------------------
extern "C" void kernel_launch(void* const* d_in, const int* in_sizes, int n_in,
                              void* d_out, int out_size, void* d_ws, size_t ws_size,
                              hipStream_t stream)
{
  const float* x  = (const float*)d_in[0];
  const float* Wq = (const float*)d_in[1];
  const float* bq = (const float*)d_in[2];
  const float* Wk = (const float*)d_in[3];
  const float* bk = (const float*)d_in[4];
  const float* Wv = (const float*)d_in[5];
  const float* bv = (const float*)d_in[6];
  const float* Wo = (const float*)d_in[7];
  const float* bo = (const float*)d_in[8];
  float* out = (float*)d_out;

  char* p = (char*)d_ws;
  auto take = [&](size_t bytes) { char* q = p; p += (bytes + 255) & ~(size_t)255; return q; };
  u16* WqT = (u16*)take((size_t)HID * HID * 2);
  u16* WkT = (u16*)take((size_t)HID * HID * 2);
  u16* WvT = (u16*)take((size_t)HID * HID * 2);
  u16* WoT = (u16*)take((size_t)HID * HID * 2);
  u16* QF  = (u16*)take((size_t)Bsz * Ssz * HID * 2);   // later aliased as Y
  u16* KFb = (u16*)take((size_t)Bsz * Ssz * HID * 2);
  u16* Vb  = (u16*)take((size_t)Bsz * Ssz * HID * 2);
  u16* KVT = (u16*)take((size_t)Bsz * NCh * Hn * Dh * Dh * 2);
  float* KS = (float*)take((size_t)Bsz * NCh * Hn * Dh * 4);
  u16* Yb = QF;   // safe alias: pass2 stages its QF rows into LDS before writing Y

  dim3 blk(256, 1, 1);
  transpose4<<<dim3(HID / 64, HID / 64, 4), blk, 0, stream>>>(
      Wq, Wk, Wv, Wo, WqT, WkT, WvT, WoT);
  gemm_bias<1, 0><<<dim3(HID / 128, (Bsz * Ssz) / 128, 3), blk, 0, stream>>>(
      x, WqT, WkT, WvT, bq, bk, bv, QF, KFb, Vb, 0x3);
  pass1_kv<<<dim3(Bsz * NCh * Hn), blk, 0, stream>>>(KFb, Vb, KVT, KS);
  cumsum_kv<<<dim3((Bsz * Hn * Dh * Dh) / 256), blk, 0, stream>>>(KVT);
  cumsum_ks<<<dim3((Bsz * Hn * Dh) / 256), blk, 0, stream>>>(KS);
  pass2_attn<<<dim3(Bsz * NCh * Hn), blk, 0, stream>>>(QF, KFb, Vb, KVT, KS, Yb);
  gemm_bias<0, 1><<<dim3(HID / 128, (Bsz * Ssz) / 128, 1), blk, 0, stream>>>(
      Yb, WoT, WoT, WoT, bo, bo, bo, out, out, out, 0);
}

// Round 4
// 523.033 us; speedup vs baseline: 1.0417x; 1.0417x over previous
//
#include <hip/hip_runtime.h>

typedef unsigned short u16;
typedef unsigned int u32;
typedef unsigned long long u64;
typedef __attribute__((ext_vector_type(8))) short short8;
typedef __attribute__((ext_vector_type(4))) float f32x4;
typedef __attribute__((ext_vector_type(4))) int int4v;

constexpr int Bsz = 2, Ssz = 4096, Hn = 16, Dh = 128, HID = 2048;
constexpr int Cch = 128, NCh = 32;
constexpr float EPSf = 1e-6f;

__device__ __forceinline__ float b2f(u16 u) {
  unsigned int i = ((unsigned int)u) << 16;
  return __builtin_bit_cast(float, i);
}
__device__ __forceinline__ u16 f2b(float f) {
  unsigned int i = __builtin_bit_cast(unsigned int, f);
  i += 0x7fffu + ((i >> 16) & 1u);   // round-to-nearest-even
  return (u16)(i >> 16);
}

// async global->LDS, 16 B per lane; LDS dest = wave-uniform base + lane*16.
// Builtin form (m97-verified): compiler emits global_load_lds_dwordx4 and
// handles M0 setup itself.
__device__ __forceinline__ void gload_lds16(const u16* g, u16* l) {
  __builtin_amdgcn_global_load_lds(
      (const __attribute__((address_space(1))) u32*)g,
      (__attribute__((address_space(3))) u32*)l, 16, 0, 0);
}

// ---------------------------------------------------------------------------
// x f32 -> bf16 (streaming, vectorized)
// ---------------------------------------------------------------------------
__global__ __launch_bounds__(256) void cvt_bf16(const float* __restrict__ x,
                                                u16* __restrict__ xb)
{
  const size_t n8 = (size_t)Bsz * Ssz * HID / 8;
  for (size_t i = (size_t)blockIdx.x * 256 + threadIdx.x; i < n8;
       i += (size_t)gridDim.x * 256) {
    const f32x4 a = *(const f32x4*)&x[i * 8];
    const f32x4 b = *(const f32x4*)&x[i * 8 + 4];
    u16 tmp[8];
#pragma unroll
    for (int u = 0; u < 4; ++u) { tmp[u] = f2b(a[u]); tmp[u + 4] = f2b(b[u]); }
    *(int4v*)&xb[i * 8] = *(const int4v*)tmp;
  }
}

// ---------------------------------------------------------------------------
// Weight transpose+convert: W f32 [K][N] -> WT bf16 [N][K], 64x64 tiles.
// ---------------------------------------------------------------------------
__global__ __launch_bounds__(256) void transpose4(
    const float* __restrict__ A0, const float* __restrict__ A1,
    const float* __restrict__ A2, const float* __restrict__ A3,
    u16* __restrict__ T0, u16* __restrict__ T1,
    u16* __restrict__ T2, u16* __restrict__ T3)
{
  constexpr int N = HID, LDT = 72;
  const int z = blockIdx.z;
  const float* __restrict__ A = (z == 0) ? A0 : (z == 1) ? A1 : (z == 2) ? A2 : A3;
  u16* __restrict__ T = (z == 0) ? T0 : (z == 1) ? T1 : (z == 2) ? T2 : T3;
  __shared__ u16 lds[64 * LDT];
  const int t = threadIdx.x;
  const int i = t >> 3, j = (t & 7) * 8;
  const int r0 = blockIdx.y * 64, c0 = blockIdx.x * 64;
#pragma unroll
  for (int half = 0; half < 2; ++half) {
    const int r = i + half * 32;
    const f32x4 a = *(const f32x4*)&A[(size_t)(r0 + r) * N + c0 + j];
    const f32x4 b = *(const f32x4*)&A[(size_t)(r0 + r) * N + c0 + j + 4];
    u16 tmp[8];
#pragma unroll
    for (int u = 0; u < 4; ++u) { tmp[u] = f2b(a[u]); tmp[u + 4] = f2b(b[u]); }
    *(int4v*)&lds[r * LDT + j] = *(const int4v*)tmp;
  }
  __syncthreads();
#pragma unroll
  for (int half = 0; half < 2; ++half) {
    const int c = i + half * 32;
    u16 tmp[8];
#pragma unroll
    for (int u = 0; u < 8; ++u) tmp[u] = lds[(j + u) * LDT + c];
    *(int4v*)&T[(size_t)(c0 + c) * N + r0 + j] = *(const int4v*)tmp;
  }
}

// ---------------------------------------------------------------------------
// GEMM (m97 structure): A bf16 [M][K] x WT bf16 [N][K] -> out[m][n] + bias,
// optional elu(x)+1. 128x128 tile, BK=64, 4 waves 2x2, global_load_lds w16,
// linear LDS, single buffer, 2 barriers/K-step. XCD-swizzled block mapping.
// ---------------------------------------------------------------------------
template <int OUTF32>
__global__ __launch_bounds__(256) void gemm_lds(
    const u16* __restrict__ A,
    const u16* __restrict__ W0T, const u16* __restrict__ W1T, const u16* __restrict__ W2T,
    const float* __restrict__ bb0, const float* __restrict__ bb1, const float* __restrict__ bb2,
    void* __restrict__ o0, void* __restrict__ o1, void* __restrict__ o2,
    int elu_mask)
{
  constexpr int K = HID, N = HID, BK = 64;
  const int z = blockIdx.z;
  const u16* __restrict__ WT    = (z == 0) ? W0T : (z == 1) ? W1T : W2T;
  const float* __restrict__ bias = (z == 0) ? bb0 : (z == 1) ? bb1 : bb2;
  void* __restrict__ outv = (z == 0) ? o0 : (z == 1) ? o1 : o2;
  const bool elu = (elu_mask >> z) & 1;

  __shared__ u16 lA[128 * BK];
  __shared__ u16 lB[128 * BK];

  // XCD swizzle: 1024 blocks/slice, consecutive launch ids round-robin XCDs;
  // give XCD k work ids [k*128, (k+1)*128) = 8 contiguous m-rows (A reuse in L2).
  const int lid = blockIdx.x + 16 * blockIdx.y;
  const int wlid = (lid & 7) * 128 + (lid >> 3);
  const int m0 = (wlid >> 4) * 128;
  const int n0 = (wlid & 15) * 128;

  const int t = threadIdx.x, lane = t & 63, w = t >> 6;
  const int wr = (w >> 1) * 64, wc = (w & 1) * 64;
  const int l15 = lane & 15, lg = lane >> 4;

  // staging: wave w covers tile rows [w*32, w*32+32); chunk q = 8 rows = 1024 B
  const int srow = lane >> 3, scol = (lane & 7) * 8;
  const u16* gA = A  + (size_t)(m0 + w * 32 + srow) * K + scol;
  const u16* gB = WT + (size_t)(n0 + w * 32 + srow) * K + scol;
  u16* lAw = &lA[w * 32 * BK];
  u16* lBw = &lB[w * 32 * BK];

  f32x4 acc[4][4] = {};

  for (int kt = 0; kt < K / BK; ++kt) {
#pragma unroll
    for (int q = 0; q < 4; ++q) {
      gload_lds16(gA + (size_t)q * 8 * K, lAw + q * 8 * BK);
      gload_lds16(gB + (size_t)q * 8 * K, lBw + q * 8 * BK);
    }
    asm volatile("s_waitcnt vmcnt(0)" ::: "memory");
    __syncthreads();
#pragma unroll
    for (int kk = 0; kk < 2; ++kk) {
      const int krd = kk * 32 + lg * 8;
      short8 aF[4], bF[4];
#pragma unroll
      for (int i = 0; i < 4; ++i)
        aF[i] = *(const short8*)&lA[(wr + i * 16 + l15) * BK + krd];
#pragma unroll
      for (int j = 0; j < 4; ++j)
        bF[j] = *(const short8*)&lB[(wc + j * 16 + l15) * BK + krd];
#pragma unroll
      for (int i = 0; i < 4; ++i)
#pragma unroll
        for (int j = 0; j < 4; ++j)
          acc[i][j] = __builtin_amdgcn_mfma_f32_16x16x32_bf16(aF[i], bF[j], acc[i][j], 0, 0, 0);
    }
    __syncthreads();
    gA += BK; gB += BK;
  }

#pragma unroll
  for (int j = 0; j < 4; ++j) {
    const int col = n0 + wc + j * 16 + l15;
    const float bv = bias[col];
#pragma unroll
    for (int i = 0; i < 4; ++i) {
      const int row0 = m0 + wr + i * 16 + lg * 4;
#pragma unroll
      for (int r = 0; r < 4; ++r) {
        float v = acc[i][j][r] + bv;
        if (elu) v = (v > 0.0f) ? (v + 1.0f) : __expf(v);   // elu(x)+1
        if (OUTF32) ((float*)outv)[(size_t)(row0 + r) * N + col] = v;
        else        ((u16*)outv)[(size_t)(row0 + r) * N + col] = f2b(v);
      }
    }
  }
}

// ---------------------------------------------------------------------------
// Pass 1, per (b,n,h): kvT[e][d] = sum_c v[c,e]*kf[c,d];  ksum[d] = sum_c kf[c,d]
// ---------------------------------------------------------------------------
__global__ __launch_bounds__(256) void pass1_kv(
    const u16* __restrict__ KF, const u16* __restrict__ V,
    u16* __restrict__ KVT, float* __restrict__ KSUM)
{
  constexpr int LD = 136;
  __shared__ u16 lk[128 * LD];
  __shared__ u16 lv[128 * LD];
  const int bnh = blockIdx.x;
  const int h = bnh % Hn, n = (bnh / Hn) % NCh, b = bnh / (Hn * NCh);
  const size_t rowbase = (size_t)(b * Ssz + n * Cch) * HID + h * Dh;
  const int t = threadIdx.x, lane = t & 63, w = t >> 6;
  const int wr = (w >> 1) * 64, wc = (w & 1) * 64;
  const int l15 = lane & 15, lg = lane >> 4;
  const int sr = t >> 4, sc = (t & 15) * 8;

#pragma unroll
  for (int rep = 0; rep < 8; ++rep) {
    const int r = rep * 16 + sr;
    *(int4v*)&lk[r * LD + sc] = *(const int4v*)&KF[rowbase + (size_t)r * HID + sc];
    *(int4v*)&lv[r * LD + sc] = *(const int4v*)&V[rowbase + (size_t)r * HID + sc];
  }
  __syncthreads();

  if (t < 128) {
    float s = 0.0f;
    for (int c = 0; c < 128; ++c) s += b2f(lk[c * LD + t]);
    KSUM[(size_t)bnh * Dh + t] = s;
  }

  f32x4 acc[4][4] = {};
#pragma unroll
  for (int kk = 0; kk < 4; ++kk) {
    const int cb = kk * 32 + lg * 8;
    short8 aF[4], bF[4];
#pragma unroll
    for (int i = 0; i < 4; ++i) {           // A[e][c] = v[c][e]
      const int e = wr + i * 16 + l15;
      short8 a;
#pragma unroll
      for (int u = 0; u < 8; ++u) a[u] = (short)lv[(cb + u) * LD + e];
      aF[i] = a;
    }
#pragma unroll
    for (int j = 0; j < 4; ++j) {           // B[c][d] = kf[c][d]
      const int d = wc + j * 16 + l15;
      short8 bb;
#pragma unroll
      for (int u = 0; u < 8; ++u) bb[u] = (short)lk[(cb + u) * LD + d];
      bF[j] = bb;
    }
#pragma unroll
    for (int i = 0; i < 4; ++i)
#pragma unroll
      for (int j = 0; j < 4; ++j)
        acc[i][j] = __builtin_amdgcn_mfma_f32_16x16x32_bf16(aF[i], bF[j], acc[i][j], 0, 0, 0);
  }

  u16* __restrict__ outp = KVT + (size_t)bnh * (Dh * Dh);
#pragma unroll
  for (int i = 0; i < 4; ++i) {
    const int e0 = wr + i * 16 + lg * 4;
#pragma unroll
    for (int j = 0; j < 4; ++j) {
      const int d = wc + j * 16 + l15;
#pragma unroll
      for (int r = 0; r < 4; ++r)
        outp[(size_t)(e0 + r) * Dh + d] = f2b(acc[i][j][r]);
    }
  }
}

// ---------------------------------------------------------------------------
// Exclusive cumsum over chunks, in place (f32 running sum).
// ---------------------------------------------------------------------------
__global__ __launch_bounds__(256) void cumsum_kv(u16* __restrict__ KVT) {
  const int tid = blockIdx.x * 256 + threadIdx.x;        // B*H*D*D threads
  const int ed = tid & (Dh * Dh - 1);
  const int bh = tid >> 14;
  const int h = bh % Hn, b = bh / Hn;
  const size_t base = ((size_t)(b * NCh * Hn) + h) * (Dh * Dh) + ed;
  const size_t stride = (size_t)Hn * Dh * Dh;
  float s = 0.0f;
  for (int n = 0; n < NCh; ++n) {
    const size_t idx = base + (size_t)n * stride;
    const float v = b2f(KVT[idx]);
    KVT[idx] = f2b(s);
    s += v;
  }
}

__global__ __launch_bounds__(256) void cumsum_ks(float* __restrict__ KS) {
  const int tid = blockIdx.x * 256 + threadIdx.x;        // B*H*D threads
  const int d = tid & (Dh - 1);
  const int bh = tid >> 7;
  const int h = bh % Hn, b = bh / Hn;
  const size_t base = ((size_t)(b * NCh * Hn) + h) * Dh + d;
  const size_t stride = (size_t)Hn * Dh;
  float s = 0.0f;
  for (int n = 0; n < NCh; ++n) {
    const size_t idx = base + (size_t)n * stride;
    const float v = KS[idx];
    KS[idx] = s;
    s += v;
  }
}

// ---------------------------------------------------------------------------
// Pass 2, per (b,n,h): A = tril(qf.kf^T); y = (A.v + qf.kv_ex) / (z+eps)
// Y may alias QF (block stages its QF rows into LDS before writing Y).
// ---------------------------------------------------------------------------
__global__ __launch_bounds__(256) void pass2_attn(
    const u16* __restrict__ QF, const u16* __restrict__ KF, const u16* __restrict__ V,
    const u16* __restrict__ KVT, const float* __restrict__ KSE,
    u16* __restrict__ Y)
{
  constexpr int LD = 136;
  __shared__ u16 smem[4 * 128 * LD];
  __shared__ float zbuf[128];
  u16* sQ  = smem;
  u16* sK  = smem + 128 * LD;      // kf, later reused for v
  u16* sA  = smem + 2 * 128 * LD;
  u16* sKV = smem + 3 * 128 * LD;

  const int bnh = blockIdx.x;
  const int h = bnh % Hn, n = (bnh / Hn) % NCh, b = bnh / (Hn * NCh);
  const size_t rowbase = (size_t)(b * Ssz + n * Cch) * HID + h * Dh;
  const int t = threadIdx.x, lane = t & 63, w = t >> 6;
  const int wr = (w >> 1) * 64, wc = (w & 1) * 64;
  const int l15 = lane & 15, lg = lane >> 4;
  const int sr = t >> 4, sc = (t & 15) * 8;

  const u16* __restrict__ kvsrc = KVT + (size_t)bnh * (Dh * Dh);
#pragma unroll
  for (int rep = 0; rep < 8; ++rep) {
    const int r = rep * 16 + sr;
    *(int4v*)&sQ[r * LD + sc]  = *(const int4v*)&QF[rowbase + (size_t)r * HID + sc];
    *(int4v*)&sK[r * LD + sc]  = *(const int4v*)&KF[rowbase + (size_t)r * HID + sc];
    *(int4v*)&sKV[r * LD + sc] = *(const int4v*)&kvsrc[r * Dh + sc];
  }
  __syncthreads();

  // --- QK^T ---
  f32x4 acc[4][4] = {};
#pragma unroll
  for (int kk = 0; kk < 4; ++kk) {
    const int krd = kk * 32 + lg * 8;
    short8 aF[4], bF[4];
#pragma unroll
    for (int i = 0; i < 4; ++i)
      aF[i] = *(const short8*)&sQ[(wr + i * 16 + l15) * LD + krd];
#pragma unroll
    for (int j = 0; j < 4; ++j)
      bF[j] = *(const short8*)&sK[(wc + j * 16 + l15) * LD + krd];
#pragma unroll
    for (int i = 0; i < 4; ++i)
#pragma unroll
      for (int j = 0; j < 4; ++j)
        acc[i][j] = __builtin_amdgcn_mfma_f32_16x16x32_bf16(aF[i], bF[j], acc[i][j], 0, 0, 0);
  }
  // causal mask + write A to LDS (bf16)
#pragma unroll
  for (int i = 0; i < 4; ++i) {
    const int c0 = wr + i * 16 + lg * 4;
#pragma unroll
    for (int j = 0; j < 4; ++j) {
      const int ck = wc + j * 16 + l15;
#pragma unroll
      for (int r = 0; r < 4; ++r) {
        const int c = c0 + r;
        sA[c * LD + ck] = f2b((ck <= c) ? acc[i][j][r] : 0.0f);
      }
    }
  }
  __syncthreads();

  // --- z per row (threads 0..127) + stage V over kf (all threads) ---
  if (t < 128) {
    const float* kse = KSE + (size_t)bnh * Dh;
    float zz = EPSf;
    for (int d2 = 0; d2 < 128; ++d2) zz += b2f(sQ[t * LD + d2]) * kse[d2];
    for (int ck = 0; ck < 128; ++ck) zz += b2f(sA[t * LD + ck]);
    zbuf[t] = zz;
  }
#pragma unroll
  for (int rep = 0; rep < 8; ++rep) {
    const int r = rep * 16 + sr;
    *(int4v*)&sK[r * LD + sc] = *(const int4v*)&V[rowbase + (size_t)r * HID + sc];
  }
  __syncthreads();

  // --- intra: o += A . v ---
  f32x4 o[4][4] = {};
#pragma unroll
  for (int kk = 0; kk < 4; ++kk) {
    const int krd = kk * 32 + lg * 8;
    short8 aF[4], bF[4];
#pragma unroll
    for (int i = 0; i < 4; ++i)
      aF[i] = *(const short8*)&sA[(wr + i * 16 + l15) * LD + krd];
#pragma unroll
    for (int j = 0; j < 4; ++j) {
      const int e = wc + j * 16 + l15;
      short8 bb;
#pragma unroll
      for (int u = 0; u < 8; ++u) bb[u] = (short)sK[(krd + u) * LD + e];
      bF[j] = bb;
    }
#pragma unroll
    for (int i = 0; i < 4; ++i)
#pragma unroll
      for (int j = 0; j < 4; ++j)
        o[i][j] = __builtin_amdgcn_mfma_f32_16x16x32_bf16(aF[i], bF[j], o[i][j], 0, 0, 0);
  }
  // --- inter: o += qf . kv_ex ---
#pragma unroll
  for (int kk = 0; kk < 4; ++kk) {
    const int krd = kk * 32 + lg * 8;
    short8 aF[4], bF[4];
#pragma unroll
    for (int i = 0; i < 4; ++i)
      aF[i] = *(const short8*)&sQ[(wr + i * 16 + l15) * LD + krd];
#pragma unroll
    for (int j = 0; j < 4; ++j)
      bF[j] = *(const short8*)&sKV[(wc + j * 16 + l15) * LD + krd];
#pragma unroll
    for (int i = 0; i < 4; ++i)
#pragma unroll
      for (int j = 0; j < 4; ++j)
        o[i][j] = __builtin_amdgcn_mfma_f32_16x16x32_bf16(aF[i], bF[j], o[i][j], 0, 0, 0);
  }

  // --- normalize + store y ---
#pragma unroll
  for (int i = 0; i < 4; ++i) {
    const int c0 = wr + i * 16 + lg * 4;
#pragma unroll
    for (int j = 0; j < 4; ++j) {
      const int e = wc + j * 16 + l15;
#pragma unroll
      for (int r = 0; r < 4; ++r) {
        const int c = c0 + r;
        Y[rowbase + (size_t)c * HID + e] = f2b(o[i][j][r] / zbuf[c]);
      }
    }
  }
}

// ---------------------------------------------------------------------------
extern "C" void kernel_launch(void* const* d_in, const int* in_sizes, int n_in,
                              void* d_out, int out_size, void* d_ws, size_t ws_size,
                              hipStream_t stream)
{
  const float* x  = (const float*)d_in[0];
  const float* Wq = (const float*)d_in[1];
  const float* bq = (const float*)d_in[2];
  const float* Wk = (const float*)d_in[3];
  const float* bk = (const float*)d_in[4];
  const float* Wv = (const float*)d_in[5];
  const float* bv = (const float*)d_in[6];
  const float* Wo = (const float*)d_in[7];
  const float* bo = (const float*)d_in[8];
  float* out = (float*)d_out;

  char* p = (char*)d_ws;
  auto take = [&](size_t bytes) { char* q = p; p += (bytes + 255) & ~(size_t)255; return q; };
  u16* WqT = (u16*)take((size_t)HID * HID * 2);
  u16* WkT = (u16*)take((size_t)HID * HID * 2);
  u16* WvT = (u16*)take((size_t)HID * HID * 2);
  u16* WoT = (u16*)take((size_t)HID * HID * 2);
  u16* QF  = (u16*)take((size_t)Bsz * Ssz * HID * 2);   // later aliased as Y
  u16* KFb = (u16*)take((size_t)Bsz * Ssz * HID * 2);
  u16* Vb  = (u16*)take((size_t)Bsz * Ssz * HID * 2);
  // xb (bf16 x) aliases KVT: xb is dead once the QKV GEMM finishes;
  // pass1 then overwrites the region with KVT.
  char* region = take((size_t)Bsz * Ssz * HID * 2);
  u16* xb  = (u16*)region;
  u16* KVT = (u16*)region;                               // 33.5 MB shared
  float* KS = (float*)take((size_t)Bsz * NCh * Hn * Dh * 4);
  u16* Yb = QF;   // safe alias: pass2 stages QF rows into LDS before writing Y

  dim3 blk(256, 1, 1);
  cvt_bf16<<<dim3(2048), blk, 0, stream>>>(x, xb);
  transpose4<<<dim3(HID / 64, HID / 64, 4), blk, 0, stream>>>(
      Wq, Wk, Wv, Wo, WqT, WkT, WvT, WoT);
  gemm_lds<0><<<dim3(HID / 128, (Bsz * Ssz) / 128, 3), blk, 0, stream>>>(
      xb, WqT, WkT, WvT, bq, bk, bv, QF, KFb, Vb, 0x3);
  pass1_kv<<<dim3(Bsz * NCh * Hn), blk, 0, stream>>>(KFb, Vb, KVT, KS);
  cumsum_kv<<<dim3((Bsz * Hn * Dh * Dh) / 256), blk, 0, stream>>>(KVT);
  cumsum_ks<<<dim3((Bsz * Hn * Dh) / 256), blk, 0, stream>>>(KS);
  pass2_attn<<<dim3(Bsz * NCh * Hn), blk, 0, stream>>>(QF, KFb, Vb, KVT, KS, Yb);
  gemm_lds<1><<<dim3(HID / 128, (Bsz * Ssz) / 128, 1), blk, 0, stream>>>(
      Yb, WoT, WoT, WoT, bo, bo, bo, out, out, out, 0);
}

// Round 5
// 428.353 us; speedup vs baseline: 1.2720x; 1.2210x over previous
//
#include <hip/hip_runtime.h>

typedef unsigned short u16;
typedef unsigned int u32;
typedef unsigned long long u64;
typedef __attribute__((ext_vector_type(8))) short short8;
typedef __attribute__((ext_vector_type(4))) float f32x4;
typedef __attribute__((ext_vector_type(4))) int int4v;

constexpr int Bsz = 2, Ssz = 4096, Hn = 16, Dh = 128, HID = 2048;
constexpr int Cch = 128, NCh = 32;
constexpr float EPSf = 1e-6f;

__device__ __forceinline__ float b2f(u16 u) {
  unsigned int i = ((unsigned int)u) << 16;
  return __builtin_bit_cast(float, i);
}
__device__ __forceinline__ u16 f2b(float f) {
  unsigned int i = __builtin_bit_cast(unsigned int, f);
  i += 0x7fffu + ((i >> 16) & 1u);   // round-to-nearest-even
  return (u16)(i >> 16);
}

// async global->LDS, 16 B per lane; LDS dest = wave-uniform base + lane*16.
__device__ __forceinline__ void gload_lds16(const u16* g, u16* l) {
  __builtin_amdgcn_global_load_lds(
      (const __attribute__((address_space(1))) u32*)g,
      (__attribute__((address_space(3))) u32*)l, 16, 0, 0);
}

// ---------------------------------------------------------------------------
// x f32 -> bf16 (streaming, vectorized)
// ---------------------------------------------------------------------------
__global__ __launch_bounds__(256) void cvt_bf16(const float* __restrict__ x,
                                                u16* __restrict__ xb)
{
  const size_t n8 = (size_t)Bsz * Ssz * HID / 8;
  for (size_t i = (size_t)blockIdx.x * 256 + threadIdx.x; i < n8;
       i += (size_t)gridDim.x * 256) {
    const f32x4 a = *(const f32x4*)&x[i * 8];
    const f32x4 b = *(const f32x4*)&x[i * 8 + 4];
    u16 tmp[8];
#pragma unroll
    for (int u = 0; u < 4; ++u) { tmp[u] = f2b(a[u]); tmp[u + 4] = f2b(b[u]); }
    *(int4v*)&xb[i * 8] = *(const int4v*)tmp;
  }
}

// ---------------------------------------------------------------------------
// Weight transpose+convert: W f32 [K][N] -> WT bf16 [N][K], 64x64 tiles.
// ---------------------------------------------------------------------------
__global__ __launch_bounds__(256) void transpose4(
    const float* __restrict__ A0, const float* __restrict__ A1,
    const float* __restrict__ A2, const float* __restrict__ A3,
    u16* __restrict__ T0, u16* __restrict__ T1,
    u16* __restrict__ T2, u16* __restrict__ T3)
{
  constexpr int N = HID, LDT = 72;
  const int z = blockIdx.z;
  const float* __restrict__ A = (z == 0) ? A0 : (z == 1) ? A1 : (z == 2) ? A2 : A3;
  u16* __restrict__ T = (z == 0) ? T0 : (z == 1) ? T1 : (z == 2) ? T2 : T3;
  __shared__ u16 lds[64 * LDT];
  const int t = threadIdx.x;
  const int i = t >> 3, j = (t & 7) * 8;
  const int r0 = blockIdx.y * 64, c0 = blockIdx.x * 64;
#pragma unroll
  for (int half = 0; half < 2; ++half) {
    const int r = i + half * 32;
    const f32x4 a = *(const f32x4*)&A[(size_t)(r0 + r) * N + c0 + j];
    const f32x4 b = *(const f32x4*)&A[(size_t)(r0 + r) * N + c0 + j + 4];
    u16 tmp[8];
#pragma unroll
    for (int u = 0; u < 4; ++u) { tmp[u] = f2b(a[u]); tmp[u + 4] = f2b(b[u]); }
    *(int4v*)&lds[r * LDT + j] = *(const int4v*)tmp;
  }
  __syncthreads();
#pragma unroll
  for (int half = 0; half < 2; ++half) {
    const int c = i + half * 32;
    u16 tmp[8];
#pragma unroll
    for (int u = 0; u < 8; ++u) tmp[u] = lds[(j + u) * LDT + c];
    *(int4v*)&T[(size_t)(c0 + c) * N + r0 + j] = *(const int4v*)tmp;
  }
}

// ---------------------------------------------------------------------------
// GEMM (m97 structure + T2 slot-XOR): A bf16 [M][K] x WT bf16 [N][K] -> out +
// bias, optional elu(x)+1. 128x128 tile, BK=64, 4 waves 2x2, global_load_lds
// w16 with pre-swizzled per-lane global source (LDS dest linear, m173),
// XOR-swizzled fragment reads -> 2-way (free) bank access.
// ---------------------------------------------------------------------------
template <int OUTF32>
__global__ __launch_bounds__(256) void gemm_lds(
    const u16* __restrict__ A,
    const u16* __restrict__ W0T, const u16* __restrict__ W1T, const u16* __restrict__ W2T,
    const float* __restrict__ bb0, const float* __restrict__ bb1, const float* __restrict__ bb2,
    void* __restrict__ o0, void* __restrict__ o1, void* __restrict__ o2,
    int elu_mask)
{
  constexpr int K = HID, N = HID, BK = 64;
  const int z = blockIdx.z;
  const u16* __restrict__ WT    = (z == 0) ? W0T : (z == 1) ? W1T : W2T;
  const float* __restrict__ bias = (z == 0) ? bb0 : (z == 1) ? bb1 : bb2;
  void* __restrict__ outv = (z == 0) ? o0 : (z == 1) ? o1 : o2;
  const bool elu = (elu_mask >> z) & 1;

  __shared__ u16 lA[128 * BK];
  __shared__ u16 lB[128 * BK];

  // XCD swizzle: 1024 blocks/slice; give each XCD 8 contiguous m-rows.
  const int lid = blockIdx.x + 16 * blockIdx.y;
  const int wlid = (lid & 7) * 128 + (lid >> 3);
  const int m0 = (wlid >> 4) * 128;
  const int n0 = (wlid & 15) * 128;

  const int t = threadIdx.x, lane = t & 63, w = t >> 6;
  const int wr = (w >> 1) * 64, wc = (w & 1) * 64;
  const int l15 = lane & 15, lg = lane >> 4;
  const int sl = l15 & 7;            // row&7 of every fragment row this lane reads

  // staging: wave w covers tile rows [w*32, w*32+32); chunk q = 8 rows = 1024 B.
  // Global source slot is XOR'd with the destination row (lane>>3) so that the
  // linear LDS write leaves the tile slot-swizzled: LDS(r, s) = G(r, s^(r&7)).
  const int srow = lane >> 3;
  const int scol = ((lane & 7) ^ srow) * 8;
  const u16* gA = A  + (size_t)(m0 + w * 32 + srow) * K + scol;
  const u16* gB = WT + (size_t)(n0 + w * 32 + srow) * K + scol;
  u16* lAw = &lA[w * 32 * BK];
  u16* lBw = &lB[w * 32 * BK];

  f32x4 acc[4][4] = {};

  for (int kt = 0; kt < K / BK; ++kt) {
#pragma unroll
    for (int q = 0; q < 4; ++q) {
      gload_lds16(gA + (size_t)q * 8 * K, lAw + q * 8 * BK);
      gload_lds16(gB + (size_t)q * 8 * K, lBw + q * 8 * BK);
    }
    asm volatile("s_waitcnt vmcnt(0)" ::: "memory");
    __syncthreads();
#pragma unroll
    for (int kk = 0; kk < 2; ++kk) {
      // wanted K-slot (16B units) = kk*4+lg; stored at slot^(row&7)
      const int krd = (((kk << 2) | lg) ^ sl) * 8;
      short8 aF[4], bF[4];
#pragma unroll
      for (int i = 0; i < 4; ++i)
        aF[i] = *(const short8*)&lA[(wr + i * 16 + l15) * BK + krd];
#pragma unroll
      for (int j = 0; j < 4; ++j)
        bF[j] = *(const short8*)&lB[(wc + j * 16 + l15) * BK + krd];
#pragma unroll
      for (int i = 0; i < 4; ++i)
#pragma unroll
        for (int j = 0; j < 4; ++j)
          acc[i][j] = __builtin_amdgcn_mfma_f32_16x16x32_bf16(aF[i], bF[j], acc[i][j], 0, 0, 0);
    }
    __syncthreads();
    gA += BK; gB += BK;
  }

#pragma unroll
  for (int j = 0; j < 4; ++j) {
    const int col = n0 + wc + j * 16 + l15;
    const float bv = bias[col];
#pragma unroll
    for (int i = 0; i < 4; ++i) {
      const int row0 = m0 + wr + i * 16 + lg * 4;
#pragma unroll
      for (int r = 0; r < 4; ++r) {
        float v = acc[i][j][r] + bv;
        if (elu) v = (v > 0.0f) ? (v + 1.0f) : __expf(v);   // elu(x)+1
        if (OUTF32) ((float*)outv)[(size_t)(row0 + r) * N + col] = v;
        else        ((u16*)outv)[(size_t)(row0 + r) * N + col] = f2b(v);
      }
    }
  }
}

// ---------------------------------------------------------------------------
// Pass 1, per (b,n,h): kvT[e][d] = sum_c v[c,e]*kf[c,d];  ksum[d] = sum_c kf[c,d]
// ---------------------------------------------------------------------------
__global__ __launch_bounds__(256) void pass1_kv(
    const u16* __restrict__ KF, const u16* __restrict__ V,
    u16* __restrict__ KVT, float* __restrict__ KSUM)
{
  constexpr int LD = 136;
  __shared__ u16 lk[128 * LD];
  __shared__ u16 lv[128 * LD];
  const int bnh = blockIdx.x;
  const int h = bnh % Hn, n = (bnh / Hn) % NCh, b = bnh / (Hn * NCh);
  const size_t rowbase = (size_t)(b * Ssz + n * Cch) * HID + h * Dh;
  const int t = threadIdx.x, lane = t & 63, w = t >> 6;
  const int wr = (w >> 1) * 64, wc = (w & 1) * 64;
  const int l15 = lane & 15, lg = lane >> 4;
  const int sr = t >> 4, sc = (t & 15) * 8;

#pragma unroll
  for (int rep = 0; rep < 8; ++rep) {
    const int r = rep * 16 + sr;
    *(int4v*)&lk[r * LD + sc] = *(const int4v*)&KF[rowbase + (size_t)r * HID + sc];
    *(int4v*)&lv[r * LD + sc] = *(const int4v*)&V[rowbase + (size_t)r * HID + sc];
  }
  __syncthreads();

  if (t < 128) {
    float s = 0.0f;
    for (int c = 0; c < 128; ++c) s += b2f(lk[c * LD + t]);
    KSUM[(size_t)bnh * Dh + t] = s;
  }

  f32x4 acc[4][4] = {};
#pragma unroll
  for (int kk = 0; kk < 4; ++kk) {
    const int cb = kk * 32 + lg * 8;
    short8 aF[4], bF[4];
#pragma unroll
    for (int i = 0; i < 4; ++i) {           // A[e][c] = v[c][e]
      const int e = wr + i * 16 + l15;
      short8 a;
#pragma unroll
      for (int u = 0; u < 8; ++u) a[u] = (short)lv[(cb + u) * LD + e];
      aF[i] = a;
    }
#pragma unroll
    for (int j = 0; j < 4; ++j) {           // B[c][d] = kf[c][d]
      const int d = wc + j * 16 + l15;
      short8 bb;
#pragma unroll
      for (int u = 0; u < 8; ++u) bb[u] = (short)lk[(cb + u) * LD + d];
      bF[j] = bb;
    }
#pragma unroll
    for (int i = 0; i < 4; ++i)
#pragma unroll
      for (int j = 0; j < 4; ++j)
        acc[i][j] = __builtin_amdgcn_mfma_f32_16x16x32_bf16(aF[i], bF[j], acc[i][j], 0, 0, 0);
  }

  u16* __restrict__ outp = KVT + (size_t)bnh * (Dh * Dh);
#pragma unroll
  for (int i = 0; i < 4; ++i) {
    const int e0 = wr + i * 16 + lg * 4;
#pragma unroll
    for (int j = 0; j < 4; ++j) {
      const int d = wc + j * 16 + l15;
#pragma unroll
      for (int r = 0; r < 4; ++r)
        outp[(size_t)(e0 + r) * Dh + d] = f2b(acc[i][j][r]);
    }
  }
}

// ---------------------------------------------------------------------------
// Exclusive cumsum over chunks, in place (f32 running sum).
// ---------------------------------------------------------------------------
__global__ __launch_bounds__(256) void cumsum_kv(u16* __restrict__ KVT) {
  const int tid = blockIdx.x * 256 + threadIdx.x;        // B*H*D*D threads
  const int ed = tid & (Dh * Dh - 1);
  const int bh = tid >> 14;
  const int h = bh % Hn, b = bh / Hn;
  const size_t base = ((size_t)(b * NCh * Hn) + h) * (Dh * Dh) + ed;
  const size_t stride = (size_t)Hn * Dh * Dh;
  float s = 0.0f;
  for (int n = 0; n < NCh; ++n) {
    const size_t idx = base + (size_t)n * stride;
    const float v = b2f(KVT[idx]);
    KVT[idx] = f2b(s);
    s += v;
  }
}

__global__ __launch_bounds__(256) void cumsum_ks(float* __restrict__ KS) {
  const int tid = blockIdx.x * 256 + threadIdx.x;        // B*H*D threads
  const int d = tid & (Dh - 1);
  const int bh = tid >> 7;
  const int h = bh % Hn, b = bh / Hn;
  const size_t base = ((size_t)(b * NCh * Hn) + h) * Dh + d;
  const size_t stride = (size_t)Hn * Dh;
  float s = 0.0f;
  for (int n = 0; n < NCh; ++n) {
    const size_t idx = base + (size_t)n * stride;
    const float v = KS[idx];
    KS[idx] = s;
    s += v;
  }
}

// ---------------------------------------------------------------------------
// Pass 2, per (b,n,h): A = tril(qf.kf^T); y = (A.v + qf.kv_ex) / (z+eps)
// Y may alias QF (block stages its QF rows into LDS before writing Y).
// ---------------------------------------------------------------------------
__global__ __launch_bounds__(256) void pass2_attn(
    const u16* __restrict__ QF, const u16* __restrict__ KF, const u16* __restrict__ V,
    const u16* __restrict__ KVT, const float* __restrict__ KSE,
    u16* __restrict__ Y)
{
  constexpr int LD = 136;
  __shared__ u16 smem[4 * 128 * LD];
  __shared__ float zbuf[128];
  u16* sQ  = smem;
  u16* sK  = smem + 128 * LD;      // kf, later reused for v
  u16* sA  = smem + 2 * 128 * LD;
  u16* sKV = smem + 3 * 128 * LD;

  const int bnh = blockIdx.x;
  const int h = bnh % Hn, n = (bnh / Hn) % NCh, b = bnh / (Hn * NCh);
  const size_t rowbase = (size_t)(b * Ssz + n * Cch) * HID + h * Dh;
  const int t = threadIdx.x, lane = t & 63, w = t >> 6;
  const int wr = (w >> 1) * 64, wc = (w & 1) * 64;
  const int l15 = lane & 15, lg = lane >> 4;
  const int sr = t >> 4, sc = (t & 15) * 8;

  const u16* __restrict__ kvsrc = KVT + (size_t)bnh * (Dh * Dh);
#pragma unroll
  for (int rep = 0; rep < 8; ++rep) {
    const int r = rep * 16 + sr;
    *(int4v*)&sQ[r * LD + sc]  = *(const int4v*)&QF[rowbase + (size_t)r * HID + sc];
    *(int4v*)&sK[r * LD + sc]  = *(const int4v*)&KF[rowbase + (size_t)r * HID + sc];
    *(int4v*)&sKV[r * LD + sc] = *(const int4v*)&kvsrc[r * Dh + sc];
  }
  __syncthreads();

  // --- QK^T ---
  f32x4 acc[4][4] = {};
#pragma unroll
  for (int kk = 0; kk < 4; ++kk) {
    const int krd = kk * 32 + lg * 8;
    short8 aF[4], bF[4];
#pragma unroll
    for (int i = 0; i < 4; ++i)
      aF[i] = *(const short8*)&sQ[(wr + i * 16 + l15) * LD + krd];
#pragma unroll
    for (int j = 0; j < 4; ++j)
      bF[j] = *(const short8*)&sK[(wc + j * 16 + l15) * LD + krd];
#pragma unroll
    for (int i = 0; i < 4; ++i)
#pragma unroll
      for (int j = 0; j < 4; ++j)
        acc[i][j] = __builtin_amdgcn_mfma_f32_16x16x32_bf16(aF[i], bF[j], acc[i][j], 0, 0, 0);
  }
  // causal mask + write A to LDS (bf16)
#pragma unroll
  for (int i = 0; i < 4; ++i) {
    const int c0 = wr + i * 16 + lg * 4;
#pragma unroll
    for (int j = 0; j < 4; ++j) {
      const int ck = wc + j * 16 + l15;
#pragma unroll
      for (int r = 0; r < 4; ++r) {
        const int c = c0 + r;
        sA[c * LD + ck] = f2b((ck <= c) ? acc[i][j][r] : 0.0f);
      }
    }
  }
  __syncthreads();

  // --- z per row (threads 0..127) + stage V over kf (all threads) ---
  if (t < 128) {
    const float* kse = KSE + (size_t)bnh * Dh;
    float zz = EPSf;
    for (int d2 = 0; d2 < 128; ++d2) zz += b2f(sQ[t * LD + d2]) * kse[d2];
    for (int ck = 0; ck < 128; ++ck) zz += b2f(sA[t * LD + ck]);
    zbuf[t] = zz;
  }
#pragma unroll
  for (int rep = 0; rep < 8; ++rep) {
    const int r = rep * 16 + sr;
    *(int4v*)&sK[r * LD + sc] = *(const int4v*)&V[rowbase + (size_t)r * HID + sc];
  }
  __syncthreads();

  // --- intra: o += A . v ---
  f32x4 o[4][4] = {};
#pragma unroll
  for (int kk = 0; kk < 4; ++kk) {
    const int krd = kk * 32 + lg * 8;
    short8 aF[4], bF[4];
#pragma unroll
    for (int i = 0; i < 4; ++i)
      aF[i] = *(const short8*)&sA[(wr + i * 16 + l15) * LD + krd];
#pragma unroll
    for (int j = 0; j < 4; ++j) {
      const int e = wc + j * 16 + l15;
      short8 bb;
#pragma unroll
      for (int u = 0; u < 8; ++u) bb[u] = (short)sK[(krd + u) * LD + e];
      bF[j] = bb;
    }
#pragma unroll
    for (int i = 0; i < 4; ++i)
#pragma unroll
      for (int j = 0; j < 4; ++j)
        o[i][j] = __builtin_amdgcn_mfma_f32_16x16x32_bf16(aF[i], bF[j], o[i][j], 0, 0, 0);
  }
  // --- inter: o += qf . kv_ex ---
#pragma unroll
  for (int kk = 0; kk < 4; ++kk) {
    const int krd = kk * 32 + lg * 8;
    short8 aF[4], bF[4];
#pragma unroll
    for (int i = 0; i < 4; ++i)
      aF[i] = *(const short8*)&sQ[(wr + i * 16 + l15) * LD + krd];
#pragma unroll
    for (int j = 0; j < 4; ++j)
      bF[j] = *(const short8*)&sKV[(wc + j * 16 + l15) * LD + krd];
#pragma unroll
    for (int i = 0; i < 4; ++i)
#pragma unroll
      for (int j = 0; j < 4; ++j)
        o[i][j] = __builtin_amdgcn_mfma_f32_16x16x32_bf16(aF[i], bF[j], o[i][j], 0, 0, 0);
  }

  // --- normalize + store y ---
#pragma unroll
  for (int i = 0; i < 4; ++i) {
    const int c0 = wr + i * 16 + lg * 4;
#pragma unroll
    for (int j = 0; j < 4; ++j) {
      const int e = wc + j * 16 + l15;
#pragma unroll
      for (int r = 0; r < 4; ++r) {
        const int c = c0 + r;
        Y[rowbase + (size_t)c * HID + e] = f2b(o[i][j][r] / zbuf[c]);
      }
    }
  }
}

// ---------------------------------------------------------------------------
extern "C" void kernel_launch(void* const* d_in, const int* in_sizes, int n_in,
                              void* d_out, int out_size, void* d_ws, size_t ws_size,
                              hipStream_t stream)
{
  const float* x  = (const float*)d_in[0];
  const float* Wq = (const float*)d_in[1];
  const float* bq = (const float*)d_in[2];
  const float* Wk = (const float*)d_in[3];
  const float* bk = (const float*)d_in[4];
  const float* Wv = (const float*)d_in[5];
  const float* bv = (const float*)d_in[6];
  const float* Wo = (const float*)d_in[7];
  const float* bo = (const float*)d_in[8];
  float* out = (float*)d_out;

  char* p = (char*)d_ws;
  auto take = [&](size_t bytes) { char* q = p; p += (bytes + 255) & ~(size_t)255; return q; };
  u16* WqT = (u16*)take((size_t)HID * HID * 2);
  u16* WkT = (u16*)take((size_t)HID * HID * 2);
  u16* WvT = (u16*)take((size_t)HID * HID * 2);
  u16* WoT = (u16*)take((size_t)HID * HID * 2);
  u16* QF  = (u16*)take((size_t)Bsz * Ssz * HID * 2);   // later aliased as Y
  u16* KFb = (u16*)take((size_t)Bsz * Ssz * HID * 2);
  u16* Vb  = (u16*)take((size_t)Bsz * Ssz * HID * 2);
  // xb (bf16 x) aliases KVT: xb is dead once the QKV GEMM finishes.
  char* region = take((size_t)Bsz * Ssz * HID * 2);
  u16* xb  = (u16*)region;
  u16* KVT = (u16*)region;                               // 33.5 MB shared
  float* KS = (float*)take((size_t)Bsz * NCh * Hn * Dh * 4);
  u16* Yb = QF;   // safe alias: pass2 stages QF rows into LDS before writing Y

  dim3 blk(256, 1, 1);
  cvt_bf16<<<dim3(2048), blk, 0, stream>>>(x, xb);
  transpose4<<<dim3(HID / 64, HID / 64, 4), blk, 0, stream>>>(
      Wq, Wk, Wv, Wo, WqT, WkT, WvT, WoT);
  gemm_lds<0><<<dim3(HID / 128, (Bsz * Ssz) / 128, 3), blk, 0, stream>>>(
      xb, WqT, WkT, WvT, bq, bk, bv, QF, KFb, Vb, 0x3);
  pass1_kv<<<dim3(Bsz * NCh * Hn), blk, 0, stream>>>(KFb, Vb, KVT, KS);
  cumsum_kv<<<dim3((Bsz * Hn * Dh * Dh) / 256), blk, 0, stream>>>(KVT);
  cumsum_ks<<<dim3((Bsz * Hn * Dh) / 256), blk, 0, stream>>>(KS);
  pass2_attn<<<dim3(Bsz * NCh * Hn), blk, 0, stream>>>(QF, KFb, Vb, KVT, KS, Yb);
  gemm_lds<1><<<dim3(HID / 128, (Bsz * Ssz) / 128, 1), blk, 0, stream>>>(
      Yb, WoT, WoT, WoT, bo, bo, bo, out, out, out, 0);
}

// Round 6
// 425.762 us; speedup vs baseline: 1.2797x; 1.0061x over previous
//
#include <hip/hip_runtime.h>

typedef unsigned short u16;
typedef unsigned int u32;
typedef unsigned long long u64;
typedef __attribute__((ext_vector_type(8))) short short8;
typedef __attribute__((ext_vector_type(4))) float f32x4;
typedef __attribute__((ext_vector_type(4))) int int4v;

constexpr int Bsz = 2, Ssz = 4096, Hn = 16, Dh = 128, HID = 2048;
constexpr int Cch = 128, NCh = 32;
constexpr float EPSf = 1e-6f;

#define MFMA16 __builtin_amdgcn_mfma_f32_16x16x32_bf16
#define VMCNT4 asm volatile("s_waitcnt vmcnt(4)" ::: "memory")
#define VMCNT0 asm volatile("s_waitcnt vmcnt(0)" ::: "memory")

__device__ __forceinline__ float b2f(u16 u) {
  unsigned int i = ((unsigned int)u) << 16;
  return __builtin_bit_cast(float, i);
}
__device__ __forceinline__ u16 f2b(float f) {
  unsigned int i = __builtin_bit_cast(unsigned int, f);
  i += 0x7fffu + ((i >> 16) & 1u);   // round-to-nearest-even
  return (u16)(i >> 16);
}

// async global->LDS, 16 B per lane; LDS dest = wave-uniform base + lane*16.
__device__ __forceinline__ void gload_lds16(const u16* g, u16* l) {
  __builtin_amdgcn_global_load_lds(
      (const __attribute__((address_space(1))) u32*)g,
      (__attribute__((address_space(3))) u32*)l, 16, 0, 0);
}

// ---------------------------------------------------------------------------
// x f32 -> bf16 (streaming, vectorized)
// ---------------------------------------------------------------------------
__global__ __launch_bounds__(256) void cvt_bf16(const float* __restrict__ x,
                                                u16* __restrict__ xb)
{
  const size_t n8 = (size_t)Bsz * Ssz * HID / 8;
  for (size_t i = (size_t)blockIdx.x * 256 + threadIdx.x; i < n8;
       i += (size_t)gridDim.x * 256) {
    const f32x4 a = *(const f32x4*)&x[i * 8];
    const f32x4 b = *(const f32x4*)&x[i * 8 + 4];
    u16 tmp[8];
#pragma unroll
    for (int u = 0; u < 4; ++u) { tmp[u] = f2b(a[u]); tmp[u + 4] = f2b(b[u]); }
    *(int4v*)&xb[i * 8] = *(const int4v*)tmp;
  }
}

// ---------------------------------------------------------------------------
// Weight transpose+convert: W f32 [K][N] -> WT bf16 [N][K], 64x64 tiles.
// ---------------------------------------------------------------------------
__global__ __launch_bounds__(256) void transpose4(
    const float* __restrict__ A0, const float* __restrict__ A1,
    const float* __restrict__ A2, const float* __restrict__ A3,
    u16* __restrict__ T0, u16* __restrict__ T1,
    u16* __restrict__ T2, u16* __restrict__ T3)
{
  constexpr int N = HID, LDT = 72;
  const int z = blockIdx.z;
  const float* __restrict__ A = (z == 0) ? A0 : (z == 1) ? A1 : (z == 2) ? A2 : A3;
  u16* __restrict__ T = (z == 0) ? T0 : (z == 1) ? T1 : (z == 2) ? T2 : T3;
  __shared__ u16 lds[64 * LDT];
  const int t = threadIdx.x;
  const int i = t >> 3, j = (t & 7) * 8;
  const int r0 = blockIdx.y * 64, c0 = blockIdx.x * 64;
#pragma unroll
  for (int half = 0; half < 2; ++half) {
    const int r = i + half * 32;
    const f32x4 a = *(const f32x4*)&A[(size_t)(r0 + r) * N + c0 + j];
    const f32x4 b = *(const f32x4*)&A[(size_t)(r0 + r) * N + c0 + j + 4];
    u16 tmp[8];
#pragma unroll
    for (int u = 0; u < 4; ++u) { tmp[u] = f2b(a[u]); tmp[u + 4] = f2b(b[u]); }
    *(int4v*)&lds[r * LDT + j] = *(const int4v*)tmp;
  }
  __syncthreads();
#pragma unroll
  for (int half = 0; half < 2; ++half) {
    const int c = i + half * 32;
    u16 tmp[8];
#pragma unroll
    for (int u = 0; u < 8; ++u) tmp[u] = lds[(j + u) * LDT + c];
    *(int4v*)&T[(size_t)(c0 + c) * N + r0 + j] = *(const int4v*)tmp;
  }
}

// ---------------------------------------------------------------------------
// 8-phase 256x256 GEMM (T2+T3+T4+T5): A bf16 [M][K] x WT bf16 [N][K] + bias,
// optional elu(x)+1. BK=64 split in kk-halves of 32; 8 waves (2Mx4N), 512 thr.
// LDS 128 KiB dynamic: [buf][A|B][kk][256][32], slot-swizzled (^ (row>>1)&3).
// Counted vmcnt(4) before end-of-phase barriers P1/P3; raw s_barrier only.
// ---------------------------------------------------------------------------
template <int OUTF32>
__global__ __launch_bounds__(512) void gemm8p(
    const u16* __restrict__ A,
    const u16* __restrict__ W0T, const u16* __restrict__ W1T, const u16* __restrict__ W2T,
    const float* __restrict__ bb0, const float* __restrict__ bb1, const float* __restrict__ bb2,
    void* __restrict__ o0, void* __restrict__ o1, void* __restrict__ o2,
    int elu_mask)
{
  constexpr int K = HID, N = HID;
  constexpr int NT = K / 64;               // 32 K-tiles
  extern __shared__ u16 lds[];             // 65536 elems = 128 KiB

  const int z = blockIdx.z;
  const u16* __restrict__ WT    = (z == 0) ? W0T : (z == 1) ? W1T : W2T;
  const float* __restrict__ bias = (z == 0) ? bb0 : (z == 1) ? bb1 : bb2;
  void* __restrict__ outv = (z == 0) ? o0 : (z == 1) ? o1 : o2;
  const bool elu = (elu_mask >> z) & 1;

  // XCD-bijective swizzle: 256 blocks/slice, XCD k gets n-tile k x all 32 m-tiles.
  const int lid = blockIdx.x + 8 * blockIdx.y;
  const int wlid = (lid & 7) * 32 + (lid >> 3);
  const int n0 = (wlid >> 5) * 256;
  const int m0 = (wlid & 31) * 256;

  const int t = threadIdx.x, lane = t & 63, w = t >> 6;  // 8 waves
  const int wm = w >> 2, wn = w & 3;
  const int l15 = lane & 15, lg = lane >> 4;
  const int sl2 = (l15 >> 1) & 3;          // read-side swizzle key

  // staging: half = [256 rows][32 elems]; per wave-issue q: 16 rows.
  // stored slot s holds global slot s ^ ((row>>1)&3); row>>1 mod4 = (lane>>3)&3.
  const int strow = lane >> 2;                              // 0..15
  const int stslot = (lane & 3) ^ ((lane >> 3) & 3);        // swizzled src slot
  const u16* gA = A  + (size_t)(m0 + w * 16 + strow) * K + stslot * 8;
  const u16* gB = WT + (size_t)(n0 + w * 16 + strow) * K + stslot * 8;

  // LDS elem offset: buf*32768 + mat*16384 + kk*8192 + row*32 (+ slot*8)
  auto stage = [&](int buf, int mat, int h, int kt) {
    const u16* g = (mat ? gB : gA) + (size_t)kt * 64 + h * 32;
    u16* l = &lds[buf * 32768 + mat * 16384 + h * 8192 + w * 512];
    gload_lds16(g, l);                       // rows  0..127 of half (q=0)
    gload_lds16(g + (size_t)128 * K, l + 4096);  // rows 128..255 (q=1)
  };
  auto rdA = [&](int buf, int i, int kk) -> short8 {
    return *(const short8*)&lds[buf * 32768 + kk * 8192 +
                                (wm * 128 + i * 16 + l15) * 32 + ((lg ^ sl2) << 3)];
  };
  auto rdB = [&](int buf, int j, int kk) -> short8 {
    return *(const short8*)&lds[buf * 32768 + 16384 + kk * 8192 +
                                (wn * 64 + j * 16 + l15) * 32 + ((lg ^ sl2) << 3)];
  };

  f32x4 acc[8][4] = {};
  short8 aF[8], b0, b1;

  // prologue: stage tile 0 into buf 0 in per-window order (A-k0,B-k0,A-k1,B-k1)
  stage(0, 0, 0, 0);
  stage(0, 1, 0, 0);
  stage(0, 0, 1, 0);
  stage(0, 1, 1, 0);
  VMCNT4;
  __builtin_amdgcn_s_barrier();

  for (int W = 0; W < NT; ++W) {
    const int buf = W & 1, sb = buf ^ 1, kn = W + 1;
    const bool ds = kn < NT;
    // ---- P0: kk0, j0/j1 ----
#pragma unroll
    for (int i = 0; i < 8; ++i) aF[i] = rdA(buf, i, 0);
    b0 = rdB(buf, 0, 0); b1 = rdB(buf, 1, 0);
    if (ds) stage(sb, 0, 0, kn);
    __builtin_amdgcn_s_barrier();
    __builtin_amdgcn_s_setprio(1);
#pragma unroll
    for (int i = 0; i < 8; ++i) {
      acc[i][0] = MFMA16(aF[i], b0, acc[i][0], 0, 0, 0);
      acc[i][1] = MFMA16(aF[i], b1, acc[i][1], 0, 0, 0);
    }
    __builtin_amdgcn_s_setprio(0);
    __builtin_amdgcn_s_barrier();
    // ---- P1: kk0, j2/j3 ----
    b0 = rdB(buf, 2, 0); b1 = rdB(buf, 3, 0);
    if (ds) stage(sb, 1, 0, kn);
    __builtin_amdgcn_s_barrier();
    __builtin_amdgcn_s_setprio(1);
#pragma unroll
    for (int i = 0; i < 8; ++i) {
      acc[i][2] = MFMA16(aF[i], b0, acc[i][2], 0, 0, 0);
      acc[i][3] = MFMA16(aF[i], b1, acc[i][3], 0, 0, 0);
    }
    __builtin_amdgcn_s_setprio(0);
    if (ds) { VMCNT4; } else { VMCNT0; }   // guarantee this tile's kk1 halves landed
    __builtin_amdgcn_s_barrier();
    // ---- P2: kk1, j0/j1 ----
#pragma unroll
    for (int i = 0; i < 8; ++i) aF[i] = rdA(buf, i, 1);
    b0 = rdB(buf, 0, 1); b1 = rdB(buf, 1, 1);
    if (ds) stage(sb, 0, 1, kn);
    __builtin_amdgcn_s_barrier();
    __builtin_amdgcn_s_setprio(1);
#pragma unroll
    for (int i = 0; i < 8; ++i) {
      acc[i][0] = MFMA16(aF[i], b0, acc[i][0], 0, 0, 0);
      acc[i][1] = MFMA16(aF[i], b1, acc[i][1], 0, 0, 0);
    }
    __builtin_amdgcn_s_setprio(0);
    __builtin_amdgcn_s_barrier();
    // ---- P3: kk1, j2/j3 ----
    b0 = rdB(buf, 2, 1); b1 = rdB(buf, 3, 1);
    if (ds) stage(sb, 1, 1, kn);
    __builtin_amdgcn_s_barrier();
    __builtin_amdgcn_s_setprio(1);
#pragma unroll
    for (int i = 0; i < 8; ++i) {
      acc[i][2] = MFMA16(aF[i], b0, acc[i][2], 0, 0, 0);
      acc[i][3] = MFMA16(aF[i], b1, acc[i][3], 0, 0, 0);
    }
    __builtin_amdgcn_s_setprio(0);
    if (ds) { VMCNT4; __builtin_amdgcn_s_barrier(); }  // next P0's halves landed
  }

  // epilogue
#pragma unroll
  for (int j = 0; j < 4; ++j) {
    const int col = n0 + wn * 64 + j * 16 + l15;
    const float bv = bias[col];
#pragma unroll
    for (int i = 0; i < 8; ++i) {
      const int row0 = m0 + wm * 128 + i * 16 + lg * 4;
#pragma unroll
      for (int r = 0; r < 4; ++r) {
        float v = acc[i][j][r] + bv;
        if (elu) v = (v > 0.0f) ? (v + 1.0f) : __expf(v);   // elu(x)+1
        if (OUTF32) ((float*)outv)[(size_t)(row0 + r) * N + col] = v;
        else        ((u16*)outv)[(size_t)(row0 + r) * N + col] = f2b(v);
      }
    }
  }
}

// ---------------------------------------------------------------------------
// Pass 1, per (b,n,h): kvT[e][d] = sum_c v[c,e]*kf[c,d];  ksum[d] = sum_c kf[c,d]
// ---------------------------------------------------------------------------
__global__ __launch_bounds__(256) void pass1_kv(
    const u16* __restrict__ KF, const u16* __restrict__ V,
    u16* __restrict__ KVT, float* __restrict__ KSUM)
{
  constexpr int LD = 136;
  __shared__ u16 lk[128 * LD];
  __shared__ u16 lv[128 * LD];
  const int bnh = blockIdx.x;
  const int h = bnh % Hn, n = (bnh / Hn) % NCh, b = bnh / (Hn * NCh);
  const size_t rowbase = (size_t)(b * Ssz + n * Cch) * HID + h * Dh;
  const int t = threadIdx.x, lane = t & 63, w = t >> 6;
  const int wr = (w >> 1) * 64, wc = (w & 1) * 64;
  const int l15 = lane & 15, lg = lane >> 4;
  const int sr = t >> 4, sc = (t & 15) * 8;

#pragma unroll
  for (int rep = 0; rep < 8; ++rep) {
    const int r = rep * 16 + sr;
    *(int4v*)&lk[r * LD + sc] = *(const int4v*)&KF[rowbase + (size_t)r * HID + sc];
    *(int4v*)&lv[r * LD + sc] = *(const int4v*)&V[rowbase + (size_t)r * HID + sc];
  }
  __syncthreads();

  if (t < 128) {
    float s = 0.0f;
    for (int c = 0; c < 128; ++c) s += b2f(lk[c * LD + t]);
    KSUM[(size_t)bnh * Dh + t] = s;
  }

  f32x4 acc[4][4] = {};
#pragma unroll
  for (int kk = 0; kk < 4; ++kk) {
    const int cb = kk * 32 + lg * 8;
    short8 aF[4], bF[4];
#pragma unroll
    for (int i = 0; i < 4; ++i) {           // A[e][c] = v[c][e]
      const int e = wr + i * 16 + l15;
      short8 a;
#pragma unroll
      for (int u = 0; u < 8; ++u) a[u] = (short)lv[(cb + u) * LD + e];
      aF[i] = a;
    }
#pragma unroll
    for (int j = 0; j < 4; ++j) {           // B[c][d] = kf[c][d]
      const int d = wc + j * 16 + l15;
      short8 bb;
#pragma unroll
      for (int u = 0; u < 8; ++u) bb[u] = (short)lk[(cb + u) * LD + d];
      bF[j] = bb;
    }
#pragma unroll
    for (int i = 0; i < 4; ++i)
#pragma unroll
      for (int j = 0; j < 4; ++j)
        acc[i][j] = MFMA16(aF[i], bF[j], acc[i][j], 0, 0, 0);
  }

  u16* __restrict__ outp = KVT + (size_t)bnh * (Dh * Dh);
#pragma unroll
  for (int i = 0; i < 4; ++i) {
    const int e0 = wr + i * 16 + lg * 4;
#pragma unroll
    for (int j = 0; j < 4; ++j) {
      const int d = wc + j * 16 + l15;
#pragma unroll
      for (int r = 0; r < 4; ++r)
        outp[(size_t)(e0 + r) * Dh + d] = f2b(acc[i][j][r]);
    }
  }
}

// ---------------------------------------------------------------------------
// Exclusive cumsum over chunks, in place (f32 running sum).
// ---------------------------------------------------------------------------
__global__ __launch_bounds__(256) void cumsum_kv(u16* __restrict__ KVT) {
  const int tid = blockIdx.x * 256 + threadIdx.x;        // B*H*D*D threads
  const int ed = tid & (Dh * Dh - 1);
  const int bh = tid >> 14;
  const int h = bh % Hn, b = bh / Hn;
  const size_t base = ((size_t)(b * NCh * Hn) + h) * (Dh * Dh) + ed;
  const size_t stride = (size_t)Hn * Dh * Dh;
  float s = 0.0f;
  for (int n = 0; n < NCh; ++n) {
    const size_t idx = base + (size_t)n * stride;
    const float v = b2f(KVT[idx]);
    KVT[idx] = f2b(s);
    s += v;
  }
}

__global__ __launch_bounds__(256) void cumsum_ks(float* __restrict__ KS) {
  const int tid = blockIdx.x * 256 + threadIdx.x;        // B*H*D threads
  const int d = tid & (Dh - 1);
  const int bh = tid >> 7;
  const int h = bh % Hn, b = bh / Hn;
  const size_t base = ((size_t)(b * NCh * Hn) + h) * Dh + d;
  const size_t stride = (size_t)Hn * Dh;
  float s = 0.0f;
  for (int n = 0; n < NCh; ++n) {
    const size_t idx = base + (size_t)n * stride;
    const float v = KS[idx];
    KS[idx] = s;
    s += v;
  }
}

// ---------------------------------------------------------------------------
// Pass 2, per (b,n,h): A = tril(qf.kf^T); y = (A.v + qf.kv_ex) / (z+eps)
// Y may alias QF (block stages its QF rows into LDS before writing Y).
// ---------------------------------------------------------------------------
__global__ __launch_bounds__(256) void pass2_attn(
    const u16* __restrict__ QF, const u16* __restrict__ KF, const u16* __restrict__ V,
    const u16* __restrict__ KVT, const float* __restrict__ KSE,
    u16* __restrict__ Y)
{
  constexpr int LD = 136;
  __shared__ u16 smem[4 * 128 * LD];
  __shared__ float zbuf[128];
  u16* sQ  = smem;
  u16* sK  = smem + 128 * LD;      // kf, later reused for v
  u16* sA  = smem + 2 * 128 * LD;
  u16* sKV = smem + 3 * 128 * LD;

  const int bnh = blockIdx.x;
  const int h = bnh % Hn, n = (bnh / Hn) % NCh, b = bnh / (Hn * NCh);
  const size_t rowbase = (size_t)(b * Ssz + n * Cch) * HID + h * Dh;
  const int t = threadIdx.x, lane = t & 63, w = t >> 6;
  const int wr = (w >> 1) * 64, wc = (w & 1) * 64;
  const int l15 = lane & 15, lg = lane >> 4;
  const int sr = t >> 4, sc = (t & 15) * 8;

  const u16* __restrict__ kvsrc = KVT + (size_t)bnh * (Dh * Dh);
#pragma unroll
  for (int rep = 0; rep < 8; ++rep) {
    const int r = rep * 16 + sr;
    *(int4v*)&sQ[r * LD + sc]  = *(const int4v*)&QF[rowbase + (size_t)r * HID + sc];
    *(int4v*)&sK[r * LD + sc]  = *(const int4v*)&KF[rowbase + (size_t)r * HID + sc];
    *(int4v*)&sKV[r * LD + sc] = *(const int4v*)&kvsrc[r * Dh + sc];
  }
  __syncthreads();

  // --- QK^T ---
  f32x4 acc[4][4] = {};
#pragma unroll
  for (int kk = 0; kk < 4; ++kk) {
    const int krd = kk * 32 + lg * 8;
    short8 aF[4], bF[4];
#pragma unroll
    for (int i = 0; i < 4; ++i)
      aF[i] = *(const short8*)&sQ[(wr + i * 16 + l15) * LD + krd];
#pragma unroll
    for (int j = 0; j < 4; ++j)
      bF[j] = *(const short8*)&sK[(wc + j * 16 + l15) * LD + krd];
#pragma unroll
    for (int i = 0; i < 4; ++i)
#pragma unroll
      for (int j = 0; j < 4; ++j)
        acc[i][j] = MFMA16(aF[i], bF[j], acc[i][j], 0, 0, 0);
  }
  // causal mask + write A to LDS (bf16)
#pragma unroll
  for (int i = 0; i < 4; ++i) {
    const int c0 = wr + i * 16 + lg * 4;
#pragma unroll
    for (int j = 0; j < 4; ++j) {
      const int ck = wc + j * 16 + l15;
#pragma unroll
      for (int r = 0; r < 4; ++r) {
        const int c = c0 + r;
        sA[c * LD + ck] = f2b((ck <= c) ? acc[i][j][r] : 0.0f);
      }
    }
  }
  __syncthreads();

  // --- z per row (threads 0..127) + stage V over kf (all threads) ---
  if (t < 128) {
    const float* kse = KSE + (size_t)bnh * Dh;
    float zz = EPSf;
    for (int d2 = 0; d2 < 128; ++d2) zz += b2f(sQ[t * LD + d2]) * kse[d2];
    for (int ck = 0; ck < 128; ++ck) zz += b2f(sA[t * LD + ck]);
    zbuf[t] = zz;
  }
#pragma unroll
  for (int rep = 0; rep < 8; ++rep) {
    const int r = rep * 16 + sr;
    *(int4v*)&sK[r * LD + sc] = *(const int4v*)&V[rowbase + (size_t)r * HID + sc];
  }
  __syncthreads();

  // --- intra: o += A . v ---
  f32x4 o[4][4] = {};
#pragma unroll
  for (int kk = 0; kk < 4; ++kk) {
    const int krd = kk * 32 + lg * 8;
    short8 aF[4], bF[4];
#pragma unroll
    for (int i = 0; i < 4; ++i)
      aF[i] = *(const short8*)&sA[(wr + i * 16 + l15) * LD + krd];
#pragma unroll
    for (int j = 0; j < 4; ++j) {
      const int e = wc + j * 16 + l15;
      short8 bb;
#pragma unroll
      for (int u = 0; u < 8; ++u) bb[u] = (short)sK[(krd + u) * LD + e];
      bF[j] = bb;
    }
#pragma unroll
    for (int i = 0; i < 4; ++i)
#pragma unroll
      for (int j = 0; j < 4; ++j)
        o[i][j] = MFMA16(aF[i], bF[j], o[i][j], 0, 0, 0);
  }
  // --- inter: o += qf . kv_ex ---
#pragma unroll
  for (int kk = 0; kk < 4; ++kk) {
    const int krd = kk * 32 + lg * 8;
    short8 aF[4], bF[4];
#pragma unroll
    for (int i = 0; i < 4; ++i)
      aF[i] = *(const short8*)&sQ[(wr + i * 16 + l15) * LD + krd];
#pragma unroll
    for (int j = 0; j < 4; ++j)
      bF[j] = *(const short8*)&sKV[(wc + j * 16 + l15) * LD + krd];
#pragma unroll
    for (int i = 0; i < 4; ++i)
#pragma unroll
      for (int j = 0; j < 4; ++j)
        o[i][j] = MFMA16(aF[i], bF[j], o[i][j], 0, 0, 0);
  }

  // --- normalize + store y ---
#pragma unroll
  for (int i = 0; i < 4; ++i) {
    const int c0 = wr + i * 16 + lg * 4;
#pragma unroll
    for (int j = 0; j < 4; ++j) {
      const int e = wc + j * 16 + l15;
#pragma unroll
      for (int r = 0; r < 4; ++r) {
        const int c = c0 + r;
        Y[rowbase + (size_t)c * HID + e] = f2b(o[i][j][r] / zbuf[c]);
      }
    }
  }
}

// ---------------------------------------------------------------------------
extern "C" void kernel_launch(void* const* d_in, const int* in_sizes, int n_in,
                              void* d_out, int out_size, void* d_ws, size_t ws_size,
                              hipStream_t stream)
{
  const float* x  = (const float*)d_in[0];
  const float* Wq = (const float*)d_in[1];
  const float* bq = (const float*)d_in[2];
  const float* Wk = (const float*)d_in[3];
  const float* bk = (const float*)d_in[4];
  const float* Wv = (const float*)d_in[5];
  const float* bv = (const float*)d_in[6];
  const float* Wo = (const float*)d_in[7];
  const float* bo = (const float*)d_in[8];
  float* out = (float*)d_out;

  char* p = (char*)d_ws;
  auto take = [&](size_t bytes) { char* q = p; p += (bytes + 255) & ~(size_t)255; return q; };
  u16* WqT = (u16*)take((size_t)HID * HID * 2);
  u16* WkT = (u16*)take((size_t)HID * HID * 2);
  u16* WvT = (u16*)take((size_t)HID * HID * 2);
  u16* WoT = (u16*)take((size_t)HID * HID * 2);
  u16* QF  = (u16*)take((size_t)Bsz * Ssz * HID * 2);   // later aliased as Y
  u16* KFb = (u16*)take((size_t)Bsz * Ssz * HID * 2);
  u16* Vb  = (u16*)take((size_t)Bsz * Ssz * HID * 2);
  // xb (bf16 x) aliases KVT: xb is dead once the QKV GEMM finishes.
  char* region = take((size_t)Bsz * Ssz * HID * 2);
  u16* xb  = (u16*)region;
  u16* KVT = (u16*)region;                               // 33.5 MB shared
  float* KS = (float*)take((size_t)Bsz * NCh * Hn * Dh * 4);
  u16* Yb = QF;   // safe alias: pass2 stages QF rows into LDS before writing Y

  // 128 KiB dynamic LDS for the 8-phase GEMM (host-side attr set; capture-safe)
  (void)hipFuncSetAttribute((const void*)gemm8p<0>,
                            hipFuncAttributeMaxDynamicSharedMemorySize, 131072);
  (void)hipFuncSetAttribute((const void*)gemm8p<1>,
                            hipFuncAttributeMaxDynamicSharedMemorySize, 131072);

  dim3 blk(256, 1, 1);
  cvt_bf16<<<dim3(2048), blk, 0, stream>>>(x, xb);
  transpose4<<<dim3(HID / 64, HID / 64, 4), blk, 0, stream>>>(
      Wq, Wk, Wv, Wo, WqT, WkT, WvT, WoT);
  gemm8p<0><<<dim3(HID / 256, (Bsz * Ssz) / 256, 3), dim3(512), 131072, stream>>>(
      xb, WqT, WkT, WvT, bq, bk, bv, QF, KFb, Vb, 0x3);
  pass1_kv<<<dim3(Bsz * NCh * Hn), blk, 0, stream>>>(KFb, Vb, KVT, KS);
  cumsum_kv<<<dim3((Bsz * Hn * Dh * Dh) / 256), blk, 0, stream>>>(KVT);
  cumsum_ks<<<dim3((Bsz * Hn * Dh) / 256), blk, 0, stream>>>(KS);
  pass2_attn<<<dim3(Bsz * NCh * Hn), blk, 0, stream>>>(QF, KFb, Vb, KVT, KS, Yb);
  gemm8p<1><<<dim3(HID / 256, (Bsz * Ssz) / 256, 1), dim3(512), 131072, stream>>>(
      Yb, WoT, WoT, WoT, bo, bo, bo, out, out, out, 0);
}

// Round 7
// 418.484 us; speedup vs baseline: 1.3020x; 1.0174x over previous
//
#include <hip/hip_runtime.h>

typedef unsigned short u16;
typedef unsigned int u32;
typedef unsigned long long u64;
typedef __attribute__((ext_vector_type(8))) short short8;
typedef __attribute__((ext_vector_type(4))) float f32x4;
typedef __attribute__((ext_vector_type(4))) int int4v;

constexpr int Bsz = 2, Ssz = 4096, Hn = 16, Dh = 128, HID = 2048;
constexpr int Cch = 128, NCh = 32;
constexpr float EPSf = 1e-6f;

#define MFMA16 __builtin_amdgcn_mfma_f32_16x16x32_bf16
#define VMCNT4 asm volatile("s_waitcnt vmcnt(4)" ::: "memory")
#define VMCNT0 asm volatile("s_waitcnt vmcnt(0)" ::: "memory")

__device__ __forceinline__ float b2f(u16 u) {
  unsigned int i = ((unsigned int)u) << 16;
  return __builtin_bit_cast(float, i);
}
__device__ __forceinline__ u16 f2b(float f) {
  unsigned int i = __builtin_bit_cast(unsigned int, f);
  i += 0x7fffu + ((i >> 16) & 1u);   // round-to-nearest-even
  return (u16)(i >> 16);
}

// async global->LDS, 16 B per lane; LDS dest = wave-uniform base + lane*16.
__device__ __forceinline__ void gload_lds16(const u16* g, u16* l) {
  __builtin_amdgcn_global_load_lds(
      (const __attribute__((address_space(1))) u32*)g,
      (__attribute__((address_space(3))) u32*)l, 16, 0, 0);
}

// ---------------------------------------------------------------------------
// x f32 -> bf16 (streaming, vectorized)
// ---------------------------------------------------------------------------
__global__ __launch_bounds__(256) void cvt_bf16(const float* __restrict__ x,
                                                u16* __restrict__ xb)
{
  const size_t n8 = (size_t)Bsz * Ssz * HID / 8;
  for (size_t i = (size_t)blockIdx.x * 256 + threadIdx.x; i < n8;
       i += (size_t)gridDim.x * 256) {
    const f32x4 a = *(const f32x4*)&x[i * 8];
    const f32x4 b = *(const f32x4*)&x[i * 8 + 4];
    u16 tmp[8];
#pragma unroll
    for (int u = 0; u < 4; ++u) { tmp[u] = f2b(a[u]); tmp[u + 4] = f2b(b[u]); }
    *(int4v*)&xb[i * 8] = *(const int4v*)tmp;
  }
}

// ---------------------------------------------------------------------------
// Weight transpose+convert: W f32 [K][N] -> WT bf16 [N][K], 64x64 tiles.
// ---------------------------------------------------------------------------
__global__ __launch_bounds__(256) void transpose4(
    const float* __restrict__ A0, const float* __restrict__ A1,
    const float* __restrict__ A2, const float* __restrict__ A3,
    u16* __restrict__ T0, u16* __restrict__ T1,
    u16* __restrict__ T2, u16* __restrict__ T3)
{
  constexpr int N = HID, LDT = 72;
  const int z = blockIdx.z;
  const float* __restrict__ A = (z == 0) ? A0 : (z == 1) ? A1 : (z == 2) ? A2 : A3;
  u16* __restrict__ T = (z == 0) ? T0 : (z == 1) ? T1 : (z == 2) ? T2 : T3;
  __shared__ u16 lds[64 * LDT];
  const int t = threadIdx.x;
  const int i = t >> 3, j = (t & 7) * 8;
  const int r0 = blockIdx.y * 64, c0 = blockIdx.x * 64;
#pragma unroll
  for (int half = 0; half < 2; ++half) {
    const int r = i + half * 32;
    const f32x4 a = *(const f32x4*)&A[(size_t)(r0 + r) * N + c0 + j];
    const f32x4 b = *(const f32x4*)&A[(size_t)(r0 + r) * N + c0 + j + 4];
    u16 tmp[8];
#pragma unroll
    for (int u = 0; u < 4; ++u) { tmp[u] = f2b(a[u]); tmp[u + 4] = f2b(b[u]); }
    *(int4v*)&lds[r * LDT + j] = *(const int4v*)tmp;
  }
  __syncthreads();
#pragma unroll
  for (int half = 0; half < 2; ++half) {
    const int c = i + half * 32;
    u16 tmp[8];
#pragma unroll
    for (int u = 0; u < 8; ++u) tmp[u] = lds[(j + u) * LDT + c];
    *(int4v*)&T[(size_t)(c0 + c) * N + r0 + j] = *(const int4v*)tmp;
  }
}

// ---------------------------------------------------------------------------
// 2-barrier/window 256x256 GEMM (T2+T4+T5): A bf16 [M][K] x WT bf16 [N][K]
// + bias, optional elu(x)+1. BK=64 in kk-halves of 32; 8 waves (2Mx4N).
// LDS 128 KiB dynamic: [buf][A|B][kk][256][32], slot-swizzled.
// Within a window buf is read-only / sb write-only -> no intra-window
// barriers needed; one vmcnt(4)+s_barrier per half-window only.
// ---------------------------------------------------------------------------
template <int OUTF32>
__global__ __launch_bounds__(512) void gemm2b(
    const u16* __restrict__ A,
    const u16* __restrict__ W0T, const u16* __restrict__ W1T, const u16* __restrict__ W2T,
    const float* __restrict__ bb0, const float* __restrict__ bb1, const float* __restrict__ bb2,
    void* __restrict__ o0, void* __restrict__ o1, void* __restrict__ o2,
    int elu_mask)
{
  constexpr int K = HID, N = HID;
  constexpr int NT = K / 64;               // 32 K-tiles
  extern __shared__ u16 lds[];             // 65536 elems = 128 KiB

  const int z = blockIdx.z;
  const u16* __restrict__ WT    = (z == 0) ? W0T : (z == 1) ? W1T : W2T;
  const float* __restrict__ bias = (z == 0) ? bb0 : (z == 1) ? bb1 : bb2;
  void* __restrict__ outv = (z == 0) ? o0 : (z == 1) ? o1 : o2;
  const bool elu = (elu_mask >> z) & 1;

  // XCD-bijective swizzle: XCD k gets n-tile k x all 32 m-tiles.
  const int lid = blockIdx.x + 8 * blockIdx.y;
  const int wlid = (lid & 7) * 32 + (lid >> 3);
  const int n0 = (wlid >> 5) * 256;
  const int m0 = (wlid & 31) * 256;

  const int t = threadIdx.x, lane = t & 63, w = t >> 6;  // 8 waves
  const int wm = w >> 2, wn = w & 3;
  const int l15 = lane & 15, lg = lane >> 4;
  const int sl2 = (l15 >> 1) & 3;          // read-side swizzle key

  // staging: stored slot s holds global slot s ^ ((row>>1)&3).
  const int strow = lane >> 2;                              // 0..15
  const int stslot = (lane & 3) ^ ((lane >> 3) & 3);        // swizzled src slot
  const u16* gA = A  + (size_t)(m0 + w * 16 + strow) * K + stslot * 8;
  const u16* gB = WT + (size_t)(n0 + w * 16 + strow) * K + stslot * 8;

  // precomputed per-thread LDS read offsets (elems)
  const int aRow = (wm * 128 + l15) * 32 + ((lg ^ sl2) << 3);
  const int bRow = 16384 + (wn * 64 + l15) * 32 + ((lg ^ sl2) << 3);
  u16* const lw = &lds[w * 512];

  f32x4 acc[8][4] = {};
  short8 aF[8], bF[4];

  // stage kk-half KKC of next tile into buffer SB (4 gloads: A q0,q1; B q0,q1)
#define STAGE(SB, KKC) do {                                                   \
    gload_lds16(gA + (KKC) * 32,                 lw + (SB)*32768 + (KKC)*8192);          \
    gload_lds16(gA + (KKC) * 32 + (size_t)128*K, lw + (SB)*32768 + (KKC)*8192 + 4096);   \
    gload_lds16(gB + (KKC) * 32,                 lw + (SB)*32768 + 16384 + (KKC)*8192);  \
    gload_lds16(gB + (KKC) * 32 + (size_t)128*K, lw + (SB)*32768 + 16384 + (KKC)*8192 + 4096); \
  } while (0)

#define HALF(BUF, KKC, PF) do {                                               \
    _Pragma("unroll")                                                         \
    for (int i = 0; i < 8; ++i)                                               \
      aF[i] = *(const short8*)&lds[(BUF)*32768 + (KKC)*8192 + aRow + i*512];  \
    _Pragma("unroll")                                                         \
    for (int j = 0; j < 4; ++j)                                               \
      bF[j] = *(const short8*)&lds[(BUF)*32768 + (KKC)*8192 + bRow + j*512];  \
    if (PF) STAGE((BUF)^1, KKC);                                              \
    __builtin_amdgcn_s_setprio(1);                                            \
    _Pragma("unroll")                                                         \
    for (int i = 0; i < 8; ++i) {                                             \
      acc[i][0] = MFMA16(aF[i], bF[0], acc[i][0], 0, 0, 0);                   \
      acc[i][1] = MFMA16(aF[i], bF[1], acc[i][1], 0, 0, 0);                   \
      acc[i][2] = MFMA16(aF[i], bF[2], acc[i][2], 0, 0, 0);                   \
      acc[i][3] = MFMA16(aF[i], bF[3], acc[i][3], 0, 0, 0);                   \
    }                                                                         \
    __builtin_amdgcn_s_setprio(0);                                            \
  } while (0)

  // prologue: stage tile 0 (kk0 then kk1) into buf0
  STAGE(0, 0);
  STAGE(0, 1);
  gA += 64; gB += 64;
  VMCNT4;                              // kk0 halves landed
  __builtin_amdgcn_s_barrier();

  for (int W = 0; W < NT; W += 2) {
    const bool p0 = (W + 1) < NT, p1 = (W + 2) < NT;
    // window W: buf0
    HALF(0, 0, p0);
    if (p0) { VMCNT4; } else { VMCNT0; }
    __builtin_amdgcn_s_barrier();
    HALF(0, 1, p0);
    if (p0) { gA += 64; gB += 64; VMCNT4; __builtin_amdgcn_s_barrier(); }
    // window W+1: buf1 (skipped if p0==false, i.e. NT odd — NT=32 even)
    if (p0) {
      HALF(1, 0, p1);
      if (p1) { VMCNT4; } else { VMCNT0; }
      __builtin_amdgcn_s_barrier();
      HALF(1, 1, p1);
      if (p1) { gA += 64; gB += 64; VMCNT4; __builtin_amdgcn_s_barrier(); }
    }
  }

  // epilogue
#pragma unroll
  for (int j = 0; j < 4; ++j) {
    const int col = n0 + wn * 64 + j * 16 + l15;
    const float bv = bias[col];
#pragma unroll
    for (int i = 0; i < 8; ++i) {
      const int row0 = m0 + wm * 128 + i * 16 + lg * 4;
#pragma unroll
      for (int r = 0; r < 4; ++r) {
        float v = acc[i][j][r] + bv;
        if (elu) v = (v > 0.0f) ? (v + 1.0f) : __expf(v);   // elu(x)+1
        if (OUTF32) ((float*)outv)[(size_t)(row0 + r) * N + col] = v;
        else        ((u16*)outv)[(size_t)(row0 + r) * N + col] = f2b(v);
      }
    }
  }
#undef STAGE
#undef HALF
}

// ---------------------------------------------------------------------------
// Pass 1, per (b,n,h): kvT[e][d] = sum_c v[c,e]*kf[c,d];  ksum[d] = sum_c kf[c,d]
// ---------------------------------------------------------------------------
__global__ __launch_bounds__(256) void pass1_kv(
    const u16* __restrict__ KF, const u16* __restrict__ V,
    u16* __restrict__ KVT, float* __restrict__ KSUM)
{
  constexpr int LD = 136;
  __shared__ u16 lk[128 * LD];
  __shared__ u16 lv[128 * LD];
  const int bnh = blockIdx.x;
  const int h = bnh % Hn, n = (bnh / Hn) % NCh, b = bnh / (Hn * NCh);
  const size_t rowbase = (size_t)(b * Ssz + n * Cch) * HID + h * Dh;
  const int t = threadIdx.x, lane = t & 63, w = t >> 6;
  const int wr = (w >> 1) * 64, wc = (w & 1) * 64;
  const int l15 = lane & 15, lg = lane >> 4;
  const int sr = t >> 4, sc = (t & 15) * 8;

#pragma unroll
  for (int rep = 0; rep < 8; ++rep) {
    const int r = rep * 16 + sr;
    *(int4v*)&lk[r * LD + sc] = *(const int4v*)&KF[rowbase + (size_t)r * HID + sc];
    *(int4v*)&lv[r * LD + sc] = *(const int4v*)&V[rowbase + (size_t)r * HID + sc];
  }
  __syncthreads();

  if (t < 128) {
    float s = 0.0f;
    for (int c = 0; c < 128; ++c) s += b2f(lk[c * LD + t]);
    KSUM[(size_t)bnh * Dh + t] = s;
  }

  f32x4 acc[4][4] = {};
#pragma unroll
  for (int kk = 0; kk < 4; ++kk) {
    const int cb = kk * 32 + lg * 8;
    short8 aF[4], bF[4];
#pragma unroll
    for (int i = 0; i < 4; ++i) {           // A[e][c] = v[c][e]
      const int e = wr + i * 16 + l15;
      short8 a;
#pragma unroll
      for (int u = 0; u < 8; ++u) a[u] = (short)lv[(cb + u) * LD + e];
      aF[i] = a;
    }
#pragma unroll
    for (int j = 0; j < 4; ++j) {           // B[c][d] = kf[c][d]
      const int d = wc + j * 16 + l15;
      short8 bb;
#pragma unroll
      for (int u = 0; u < 8; ++u) bb[u] = (short)lk[(cb + u) * LD + d];
      bF[j] = bb;
    }
#pragma unroll
    for (int i = 0; i < 4; ++i)
#pragma unroll
      for (int j = 0; j < 4; ++j)
        acc[i][j] = MFMA16(aF[i], bF[j], acc[i][j], 0, 0, 0);
  }

  u16* __restrict__ outp = KVT + (size_t)bnh * (Dh * Dh);
#pragma unroll
  for (int i = 0; i < 4; ++i) {
    const int e0 = wr + i * 16 + lg * 4;
#pragma unroll
    for (int j = 0; j < 4; ++j) {
      const int d = wc + j * 16 + l15;
#pragma unroll
      for (int r = 0; r < 4; ++r)
        outp[(size_t)(e0 + r) * Dh + d] = f2b(acc[i][j][r]);
    }
  }
}

// ---------------------------------------------------------------------------
// Exclusive cumsum over chunks, in place (f32 running sum).
// ---------------------------------------------------------------------------
__global__ __launch_bounds__(256) void cumsum_kv(u16* __restrict__ KVT) {
  const int tid = blockIdx.x * 256 + threadIdx.x;        // B*H*D*D threads
  const int ed = tid & (Dh * Dh - 1);
  const int bh = tid >> 14;
  const int h = bh % Hn, b = bh / Hn;
  const size_t base = ((size_t)(b * NCh * Hn) + h) * (Dh * Dh) + ed;
  const size_t stride = (size_t)Hn * Dh * Dh;
  float s = 0.0f;
  for (int n = 0; n < NCh; ++n) {
    const size_t idx = base + (size_t)n * stride;
    const float v = b2f(KVT[idx]);
    KVT[idx] = f2b(s);
    s += v;
  }
}

__global__ __launch_bounds__(256) void cumsum_ks(float* __restrict__ KS) {
  const int tid = blockIdx.x * 256 + threadIdx.x;        // B*H*D threads
  const int d = tid & (Dh - 1);
  const int bh = tid >> 7;
  const int h = bh % Hn, b = bh / Hn;
  const size_t base = ((size_t)(b * NCh * Hn) + h) * Dh + d;
  const size_t stride = (size_t)Hn * Dh;
  float s = 0.0f;
  for (int n = 0; n < NCh; ++n) {
    const size_t idx = base + (size_t)n * stride;
    const float v = KS[idx];
    KS[idx] = s;
    s += v;
  }
}

// ---------------------------------------------------------------------------
// Pass 2, per (b,n,h): A = tril(qf.kf^T); y = (A.v + qf.kv_ex) / (z+eps)
// Y may alias QF (block stages its QF rows into LDS before writing Y).
// ---------------------------------------------------------------------------
__global__ __launch_bounds__(256) void pass2_attn(
    const u16* __restrict__ QF, const u16* __restrict__ KF, const u16* __restrict__ V,
    const u16* __restrict__ KVT, const float* __restrict__ KSE,
    u16* __restrict__ Y)
{
  constexpr int LD = 136;
  __shared__ u16 smem[4 * 128 * LD];
  __shared__ float zbuf[128];
  u16* sQ  = smem;
  u16* sK  = smem + 128 * LD;      // kf, later reused for v
  u16* sA  = smem + 2 * 128 * LD;
  u16* sKV = smem + 3 * 128 * LD;

  const int bnh = blockIdx.x;
  const int h = bnh % Hn, n = (bnh / Hn) % NCh, b = bnh / (Hn * NCh);
  const size_t rowbase = (size_t)(b * Ssz + n * Cch) * HID + h * Dh;
  const int t = threadIdx.x, lane = t & 63, w = t >> 6;
  const int wr = (w >> 1) * 64, wc = (w & 1) * 64;
  const int l15 = lane & 15, lg = lane >> 4;
  const int sr = t >> 4, sc = (t & 15) * 8;

  const u16* __restrict__ kvsrc = KVT + (size_t)bnh * (Dh * Dh);
#pragma unroll
  for (int rep = 0; rep < 8; ++rep) {
    const int r = rep * 16 + sr;
    *(int4v*)&sQ[r * LD + sc]  = *(const int4v*)&QF[rowbase + (size_t)r * HID + sc];
    *(int4v*)&sK[r * LD + sc]  = *(const int4v*)&KF[rowbase + (size_t)r * HID + sc];
    *(int4v*)&sKV[r * LD + sc] = *(const int4v*)&kvsrc[r * Dh + sc];
  }
  __syncthreads();

  // --- QK^T ---
  f32x4 acc[4][4] = {};
#pragma unroll
  for (int kk = 0; kk < 4; ++kk) {
    const int krd = kk * 32 + lg * 8;
    short8 aF[4], bF[4];
#pragma unroll
    for (int i = 0; i < 4; ++i)
      aF[i] = *(const short8*)&sQ[(wr + i * 16 + l15) * LD + krd];
#pragma unroll
    for (int j = 0; j < 4; ++j)
      bF[j] = *(const short8*)&sK[(wc + j * 16 + l15) * LD + krd];
#pragma unroll
    for (int i = 0; i < 4; ++i)
#pragma unroll
      for (int j = 0; j < 4; ++j)
        acc[i][j] = MFMA16(aF[i], bF[j], acc[i][j], 0, 0, 0);
  }
  // causal mask + write A to LDS (bf16)
#pragma unroll
  for (int i = 0; i < 4; ++i) {
    const int c0 = wr + i * 16 + lg * 4;
#pragma unroll
    for (int j = 0; j < 4; ++j) {
      const int ck = wc + j * 16 + l15;
#pragma unroll
      for (int r = 0; r < 4; ++r) {
        const int c = c0 + r;
        sA[c * LD + ck] = f2b((ck <= c) ? acc[i][j][r] : 0.0f);
      }
    }
  }
  __syncthreads();

  // --- z per row (threads 0..127) + stage V over kf (all threads) ---
  if (t < 128) {
    const float* kse = KSE + (size_t)bnh * Dh;
    float zz = EPSf;
    for (int d2 = 0; d2 < 128; ++d2) zz += b2f(sQ[t * LD + d2]) * kse[d2];
    for (int ck = 0; ck < 128; ++ck) zz += b2f(sA[t * LD + ck]);
    zbuf[t] = zz;
  }
#pragma unroll
  for (int rep = 0; rep < 8; ++rep) {
    const int r = rep * 16 + sr;
    *(int4v*)&sK[r * LD + sc] = *(const int4v*)&V[rowbase + (size_t)r * HID + sc];
  }
  __syncthreads();

  // --- intra: o += A . v ---
  f32x4 o[4][4] = {};
#pragma unroll
  for (int kk = 0; kk < 4; ++kk) {
    const int krd = kk * 32 + lg * 8;
    short8 aF[4], bF[4];
#pragma unroll
    for (int i = 0; i < 4; ++i)
      aF[i] = *(const short8*)&sA[(wr + i * 16 + l15) * LD + krd];
#pragma unroll
    for (int j = 0; j < 4; ++j) {
      const int e = wc + j * 16 + l15;
      short8 bb;
#pragma unroll
      for (int u = 0; u < 8; ++u) bb[u] = (short)sK[(krd + u) * LD + e];
      bF[j] = bb;
    }
#pragma unroll
    for (int i = 0; i < 4; ++i)
#pragma unroll
      for (int j = 0; j < 4; ++j)
        o[i][j] = MFMA16(aF[i], bF[j], o[i][j], 0, 0, 0);
  }
  // --- inter: o += qf . kv_ex ---
#pragma unroll
  for (int kk = 0; kk < 4; ++kk) {
    const int krd = kk * 32 + lg * 8;
    short8 aF[4], bF[4];
#pragma unroll
    for (int i = 0; i < 4; ++i)
      aF[i] = *(const short8*)&sQ[(wr + i * 16 + l15) * LD + krd];
#pragma unroll
    for (int j = 0; j < 4; ++j)
      bF[j] = *(const short8*)&sKV[(wc + j * 16 + l15) * LD + krd];
#pragma unroll
    for (int i = 0; i < 4; ++i)
#pragma unroll
      for (int j = 0; j < 4; ++j)
        o[i][j] = MFMA16(aF[i], bF[j], o[i][j], 0, 0, 0);
  }

  // --- normalize + store y ---
#pragma unroll
  for (int i = 0; i < 4; ++i) {
    const int c0 = wr + i * 16 + lg * 4;
#pragma unroll
    for (int j = 0; j < 4; ++j) {
      const int e = wc + j * 16 + l15;
#pragma unroll
      for (int r = 0; r < 4; ++r) {
        const int c = c0 + r;
        Y[rowbase + (size_t)c * HID + e] = f2b(o[i][j][r] / zbuf[c]);
      }
    }
  }
}

// ---------------------------------------------------------------------------
extern "C" void kernel_launch(void* const* d_in, const int* in_sizes, int n_in,
                              void* d_out, int out_size, void* d_ws, size_t ws_size,
                              hipStream_t stream)
{
  const float* x  = (const float*)d_in[0];
  const float* Wq = (const float*)d_in[1];
  const float* bq = (const float*)d_in[2];
  const float* Wk = (const float*)d_in[3];
  const float* bk = (const float*)d_in[4];
  const float* Wv = (const float*)d_in[5];
  const float* bv = (const float*)d_in[6];
  const float* Wo = (const float*)d_in[7];
  const float* bo = (const float*)d_in[8];
  float* out = (float*)d_out;

  char* p = (char*)d_ws;
  auto take = [&](size_t bytes) { char* q = p; p += (bytes + 255) & ~(size_t)255; return q; };
  u16* WqT = (u16*)take((size_t)HID * HID * 2);
  u16* WkT = (u16*)take((size_t)HID * HID * 2);
  u16* WvT = (u16*)take((size_t)HID * HID * 2);
  u16* WoT = (u16*)take((size_t)HID * HID * 2);
  u16* QF  = (u16*)take((size_t)Bsz * Ssz * HID * 2);   // later aliased as Y
  u16* KFb = (u16*)take((size_t)Bsz * Ssz * HID * 2);
  u16* Vb  = (u16*)take((size_t)Bsz * Ssz * HID * 2);
  // xb (bf16 x) aliases KVT: xb is dead once the QKV GEMM finishes.
  char* region = take((size_t)Bsz * Ssz * HID * 2);
  u16* xb  = (u16*)region;
  u16* KVT = (u16*)region;                               // 33.5 MB shared
  float* KS = (float*)take((size_t)Bsz * NCh * Hn * Dh * 4);
  u16* Yb = QF;   // safe alias: pass2 stages QF rows into LDS before writing Y

  // 128 KiB dynamic LDS for the GEMM (host-side attr set; capture-safe)
  (void)hipFuncSetAttribute((const void*)gemm2b<0>,
                            hipFuncAttributeMaxDynamicSharedMemorySize, 131072);
  (void)hipFuncSetAttribute((const void*)gemm2b<1>,
                            hipFuncAttributeMaxDynamicSharedMemorySize, 131072);

  dim3 blk(256, 1, 1);
  cvt_bf16<<<dim3(2048), blk, 0, stream>>>(x, xb);
  transpose4<<<dim3(HID / 64, HID / 64, 4), blk, 0, stream>>>(
      Wq, Wk, Wv, Wo, WqT, WkT, WvT, WoT);
  gemm2b<0><<<dim3(HID / 256, (Bsz * Ssz) / 256, 3), dim3(512), 131072, stream>>>(
      xb, WqT, WkT, WvT, bq, bk, bv, QF, KFb, Vb, 0x3);
  pass1_kv<<<dim3(Bsz * NCh * Hn), blk, 0, stream>>>(KFb, Vb, KVT, KS);
  cumsum_kv<<<dim3((Bsz * Hn * Dh * Dh) / 256), blk, 0, stream>>>(KVT);
  cumsum_ks<<<dim3((Bsz * Hn * Dh) / 256), blk, 0, stream>>>(KS);
  pass2_attn<<<dim3(Bsz * NCh * Hn), blk, 0, stream>>>(QF, KFb, Vb, KVT, KS, Yb);
  gemm2b<1><<<dim3(HID / 256, (Bsz * Ssz) / 256, 1), dim3(512), 131072, stream>>>(
      Yb, WoT, WoT, WoT, bo, bo, bo, out, out, out, 0);
}